// Round 4
// baseline (469.516 us; speedup 1.0000x reference)
//
#include <hip/hip_runtime.h>
#include <stdint.h>

#define NT 256

__device__ __forceinline__ float lrelu(float x) { return x > 0.f ? x : 0.2f * x; }

// ---- edge dtype detection (int32 vs int64) ----
__global__ void detect_kernel(const int* __restrict__ ei, int* __restrict__ flag, int twoE) {
  __shared__ int any;
  if (threadIdx.x == 0) any = 0;
  __syncthreads();
  int n = twoE < 4096 ? twoE : 4096;
  for (int i = threadIdx.x * 2 + 1; i < n; i += 2 * NT)
    if (ei[i] != 0) any = 1;   // benign race, same value
  __syncthreads();
  if (threadIdx.x == 0) *flag = any;   // 1 -> int32 data, 0 -> int64
}

// ---- convert edges + fused dst histogram ----
__global__ void cvt_edges_kernel(const void* __restrict__ ei, int* __restrict__ out,
                                 const int* __restrict__ flag, int* __restrict__ deg,
                                 int E, int twoE) {
  int i = blockIdx.x * NT + threadIdx.x;
  if (i >= twoE) return;
  int v;
  if (*flag) v = ((const int*)ei)[i];
  else       v = (int)((const long long*)ei)[i];
  out[i] = v;
  if (i >= E) atomicAdd(&deg[v], 1);   // dst half
}

// ---- CSR build ----
__global__ void zero2_kernel(int* __restrict__ a, int* __restrict__ b, int n) {
  int i = blockIdx.x * NT + threadIdx.x;
  if (i < n) { a[i] = 0; b[i] = 0; }
}

__global__ void scan1_kernel(const int* __restrict__ deg, int* __restrict__ bsum, int N) {
  __shared__ int sm[NT];
  int idx = blockIdx.x * NT + threadIdx.x;
  sm[threadIdx.x] = (idx < N) ? deg[idx] : 0;
  __syncthreads();
  for (int s = NT / 2; s > 0; s >>= 1) {
    if (threadIdx.x < s) sm[threadIdx.x] += sm[threadIdx.x + s];
    __syncthreads();
  }
  if (threadIdx.x == 0) bsum[blockIdx.x] = sm[0];
}

__global__ void scan2_kernel(const int* __restrict__ bsum, int* __restrict__ boff, int SB) {
  __shared__ int sm[NT];
  int t = threadIdx.x;
  int v = (t < SB) ? bsum[t] : 0;
  sm[t] = v;
  __syncthreads();
  for (int s = 1; s < NT; s <<= 1) {
    int add = (t >= s) ? sm[t - s] : 0;
    __syncthreads();
    sm[t] += add;
    __syncthreads();
  }
  if (t < SB) boff[t] = sm[t] - v;   // exclusive
}

__global__ void scan3_kernel(const int* __restrict__ deg, const int* __restrict__ boff,
                             int* __restrict__ rowptr, int N) {
  __shared__ int sm[NT];
  int idx = blockIdx.x * NT + threadIdx.x;
  int v = (idx < N) ? deg[idx] : 0;
  sm[threadIdx.x] = v;
  __syncthreads();
  for (int s = 1; s < NT; s <<= 1) {
    int add = (threadIdx.x >= s) ? sm[threadIdx.x - s] : 0;
    __syncthreads();
    sm[threadIdx.x] += add;
    __syncthreads();
  }
  if (idx <= N) rowptr[idx] = boff[blockIdx.x] + sm[threadIdx.x] - v;  // exclusive scan
}

__global__ void scatter_kernel(const int* __restrict__ src, const int* __restrict__ dst,
                               const int* __restrict__ rowptr, int* __restrict__ cursor,
                               int* __restrict__ csr_src, int E) {
  int e = blockIdx.x * NT + threadIdx.x;
  if (e >= E) return;
  int d = dst[e];
  int pos = rowptr[d] + atomicAdd(&cursor[d], 1);
  csr_src[pos] = src[e];
}

// ---- layer 1 GEMM + attention dots: xl1 = x@W1, a1 = [a_l | a_r] ----
// 16 rows/block, 4 rows per wave
__global__ void __launch_bounds__(NT)
gemm1_kernel(const float* __restrict__ x, const float* __restrict__ W1,
             const float* __restrict__ attl, const float* __restrict__ attr,
             float* __restrict__ xl1, float* __restrict__ a1, int N) {
  __shared__ float Ws[128 * 64];
  __shared__ float xs[16][128];
  for (int i = threadIdx.x; i < 128 * 16; i += NT)     // float4 units of Ws
    *(float4*)&Ws[i * 4] = *(const float4*)&W1[i * 4];
  int row0 = blockIdx.x * 16;
  for (int i = threadIdx.x; i < 16 * 32; i += NT) {    // float4 units of xs
    int r = i >> 5, c4 = i & 31;
    int n = row0 + r;
    float4 v = make_float4(0.f, 0.f, 0.f, 0.f);
    if (n < N) v = *(const float4*)&x[(size_t)n * 128 + c4 * 4];
    *(float4*)&xs[r][c4 * 4] = v;
  }
  __syncthreads();
  int w = threadIdx.x >> 6;
  int lane = threadIdx.x & 63;
  float al = attl[lane], ar = attr[lane];
  for (int rr = 0; rr < 4; ++rr) {
    int n = row0 + w * 4 + rr;
    if (n >= N) break;
    float acc = 0.f;
#pragma unroll 8
    for (int k = 0; k < 128; ++k) acc += xs[w * 4 + rr][k] * Ws[k * 64 + lane];
    xl1[(size_t)n * 64 + lane] = acc;
    float pl = acc * al;
    float pr = acc * ar;
#pragma unroll
    for (int m = 1; m < 8; m <<= 1) {
      pl += __shfl_xor(pl, m, 64);
      pr += __shfl_xor(pr, m, 64);
    }
    if ((lane & 7) == 0) {
      int h = lane >> 3;
      a1[n * 16 + h] = pl;
      a1[n * 16 + 8 + h] = pr;
    }
  }
}

// ---- fold W2 with att vectors: wl[k][h] = sum_f W2[k, h*64+f]*attl2[h,f] ----
__global__ void foldw_kernel(const float* __restrict__ W2, const float* __restrict__ attl2,
                             const float* __restrict__ attr2, float* __restrict__ wl,
                             float* __restrict__ wr) {
  int t = threadIdx.x;           // 0..511
  int k = t >> 3, h = t & 7;
  float sl = 0.f, sr = 0.f;
  for (int f = 0; f < 64; ++f) {
    float w = W2[k * 512 + h * 64 + f];
    sl += w * attl2[h * 64 + f];
    sr += w * attr2[h * 64 + f];
  }
  wl[k * 8 + h] = sl;
  wr[k * 8 + h] = sr;
}

// ---- Wt2[hk][f] = W2[k, h*64+f] * 0.125  (coalesced over f) ----
__global__ void foldWt_kernel(const float* __restrict__ W2, float* __restrict__ Wt2) {
  int idx = blockIdx.x * NT + threadIdx.x;   // over 512*64
  if (idx >= 512 * 64) return;
  int f = idx & 63;
  int hk = idx >> 6;           // h*64+k
  int h = hk >> 6, k = hk & 63;
  Wt2[idx] = W2[k * 512 + h * 64 + f] * 0.125f;
}

// ---- layer1: single-pass softmax+aggregation, LDS-staged edge weights ----
// one wave per node; lane = h*8+f
__global__ void __launch_bounds__(NT)
node_aggr1_kernel(const int* __restrict__ rowptr, const int* __restrict__ csr_src,
                  const float* __restrict__ a1, const float* __restrict__ xl1,
                  const float* __restrict__ b1, const float* __restrict__ wl,
                  const float* __restrict__ wr, float* __restrict__ hr,
                  float* __restrict__ a2, int N) {
  __shared__ float ps[4][64][8];
  __shared__ int ss[4][64];
  int w = threadIdx.x >> 6;
  int n = blockIdx.x * 4 + w;
  if (n >= N) return;
  int lane = threadIdx.x & 63;
  int hown = lane >> 3;
  int base = rowptr[n];
  int deg = rowptr[n + 1] - base;

  float4 r0 = *(const float4*)(a1 + n * 16 + 8);
  float4 r1 = *(const float4*)(a1 + n * 16 + 12);
  float ar[8] = {r0.x, r0.y, r0.z, r0.w, r1.x, r1.y, r1.z, r1.w};

  float acc = 0.f;
  float dnl[8] = {0.f, 0.f, 0.f, 0.f, 0.f, 0.f, 0.f, 0.f};

  for (int j0 = 0; j0 < deg; j0 += 64) {
    int cnt = deg - j0; if (cnt > 64) cnt = 64;
    if (lane < cnt) {
      int s = csr_src[base + j0 + lane];
      ss[w][lane] = s;
      float4 l0 = *(const float4*)(a1 + s * 16);
      float4 l1 = *(const float4*)(a1 + s * 16 + 4);
      float p0 = __expf(lrelu(l0.x + ar[0]));
      float p1 = __expf(lrelu(l0.y + ar[1]));
      float p2 = __expf(lrelu(l0.z + ar[2]));
      float p3 = __expf(lrelu(l0.w + ar[3]));
      float p4 = __expf(lrelu(l1.x + ar[4]));
      float p5 = __expf(lrelu(l1.y + ar[5]));
      float p6 = __expf(lrelu(l1.z + ar[6]));
      float p7 = __expf(lrelu(l1.w + ar[7]));
      dnl[0] += p0; dnl[1] += p1; dnl[2] += p2; dnl[3] += p3;
      dnl[4] += p4; dnl[5] += p5; dnl[6] += p6; dnl[7] += p7;
      *(float4*)&ps[w][lane][0] = make_float4(p0, p1, p2, p3);
      *(float4*)&ps[w][lane][4] = make_float4(p4, p5, p6, p7);
    }
    asm volatile("s_waitcnt lgkmcnt(0)" ::: "memory");
    for (int j = 0; j < cnt; ++j) {
      int s = ss[w][j];
      float p = ps[w][j][hown];
      acc += p * xl1[(size_t)s * 64 + lane];
    }
  }
  // reduce denominators across lanes (each lane holds partials for its staged edges)
#pragma unroll
  for (int m = 1; m < 64; m <<= 1) {
#pragma unroll
    for (int h = 0; h < 8; ++h) dnl[h] += __shfl_xor(dnl[h], m, 64);
  }
  float dnh = dnl[0];
#pragma unroll
  for (int h = 1; h < 8; ++h) if (hown == h) dnh = dnl[h];

  acc = acc / (dnh + 1e-16f);
  float hv = fmaxf(acc + b1[lane], 0.f);   // relu(out1 + b1)
  hr[(size_t)n * 64 + lane] = hv;

  // layer-2 attention dots: a2l[h] = sum_k hv_k * wl[k][h]
  float tl[8], tr[8];
#pragma unroll
  for (int h2 = 0; h2 < 8; ++h2) { tl[h2] = hv * wl[lane * 8 + h2]; tr[h2] = hv * wr[lane * 8 + h2]; }
#pragma unroll
  for (int m = 1; m < 64; m <<= 1) {
#pragma unroll
    for (int h2 = 0; h2 < 8; ++h2) { tl[h2] += __shfl_xor(tl[h2], m, 64); tr[h2] += __shfl_xor(tr[h2], m, 64); }
  }
  if (lane == 0) {
#pragma unroll
    for (int h2 = 0; h2 < 8; ++h2) {
      a2[n * 16 + h2] = tl[h2];
      a2[n * 16 + 8 + h2] = tr[h2];
    }
  }
}

// ---- layer2: single-pass softmax+aggregation -> normalized g[n,512] ----
// one wave per node; lane = k (feature within head)
__global__ void __launch_bounds__(NT)
node_aggr2_kernel(const int* __restrict__ rowptr, const int* __restrict__ csr_src,
                  const float* __restrict__ a2, const float* __restrict__ hr,
                  float* __restrict__ g, int N) {
  __shared__ float ps[4][64][8];
  __shared__ int ss[4][64];
  int w = threadIdx.x >> 6;
  int n = blockIdx.x * 4 + w;
  if (n >= N) return;
  int lane = threadIdx.x & 63;
  int base = rowptr[n];
  int deg = rowptr[n + 1] - base;

  float4 r0 = *(const float4*)(a2 + n * 16 + 8);
  float4 r1 = *(const float4*)(a2 + n * 16 + 12);
  float ar[8] = {r0.x, r0.y, r0.z, r0.w, r1.x, r1.y, r1.z, r1.w};

  float acc[8] = {0.f, 0.f, 0.f, 0.f, 0.f, 0.f, 0.f, 0.f};
  float dnl[8] = {0.f, 0.f, 0.f, 0.f, 0.f, 0.f, 0.f, 0.f};

  for (int j0 = 0; j0 < deg; j0 += 64) {
    int cnt = deg - j0; if (cnt > 64) cnt = 64;
    if (lane < cnt) {
      int s = csr_src[base + j0 + lane];
      ss[w][lane] = s;
      float4 l0 = *(const float4*)(a2 + s * 16);
      float4 l1 = *(const float4*)(a2 + s * 16 + 4);
      float p0 = __expf(lrelu(l0.x + ar[0]));
      float p1 = __expf(lrelu(l0.y + ar[1]));
      float p2 = __expf(lrelu(l0.z + ar[2]));
      float p3 = __expf(lrelu(l0.w + ar[3]));
      float p4 = __expf(lrelu(l1.x + ar[4]));
      float p5 = __expf(lrelu(l1.y + ar[5]));
      float p6 = __expf(lrelu(l1.z + ar[6]));
      float p7 = __expf(lrelu(l1.w + ar[7]));
      dnl[0] += p0; dnl[1] += p1; dnl[2] += p2; dnl[3] += p3;
      dnl[4] += p4; dnl[5] += p5; dnl[6] += p6; dnl[7] += p7;
      *(float4*)&ps[w][lane][0] = make_float4(p0, p1, p2, p3);
      *(float4*)&ps[w][lane][4] = make_float4(p4, p5, p6, p7);
    }
    asm volatile("s_waitcnt lgkmcnt(0)" ::: "memory");
    for (int j = 0; j < cnt; ++j) {
      int s = ss[w][j];
      float hv = hr[(size_t)s * 64 + lane];
      float4 pa = *(const float4*)&ps[w][j][0];
      float4 pb = *(const float4*)&ps[w][j][4];
      acc[0] += pa.x * hv; acc[1] += pa.y * hv; acc[2] += pa.z * hv; acc[3] += pa.w * hv;
      acc[4] += pb.x * hv; acc[5] += pb.y * hv; acc[6] += pb.z * hv; acc[7] += pb.w * hv;
    }
  }
#pragma unroll
  for (int m = 1; m < 64; m <<= 1) {
#pragma unroll
    for (int h = 0; h < 8; ++h) dnl[h] += __shfl_xor(dnl[h], m, 64);
  }
#pragma unroll
  for (int h = 0; h < 8; ++h) {
    float v = acc[h] * (1.f / (dnl[h] + 1e-16f));
    g[(size_t)n * 512 + h * 64 + lane] = v;
  }
}

// ---- tiled fp32 GEMM: out[N,64] = g[N,512] @ Wt2[512,64] + b2 ----
// 64 rows/block, both operands LDS-staged in k-chunks of 128
__global__ void __launch_bounds__(NT)
gemm3_kernel(const float* __restrict__ g, const float* __restrict__ Wt2,
             const float* __restrict__ b2, float* __restrict__ out, int N) {
  __shared__ float gs[64][128];   // 32 KB
  __shared__ float ws[128][64];   // 32 KB
  int row0 = blockIdx.x * 64;
  int lane = threadIdx.x & 63;
  int w = threadIdx.x >> 6;
  float acc[16];
#pragma unroll
  for (int r = 0; r < 16; ++r) acc[r] = 0.f;

  for (int k0 = 0; k0 < 512; k0 += 128) {
    __syncthreads();
    for (int i = threadIdx.x; i < 128 * 16; i += NT)       // ws float4 units
      *(float4*)&ws[0][i * 4] = *(const float4*)&Wt2[k0 * 64 + i * 4];
    for (int i = threadIdx.x; i < 64 * 32; i += NT) {      // gs float4 units
      int r = i >> 5, c4 = i & 31;
      int n = row0 + r;
      float4 v = make_float4(0.f, 0.f, 0.f, 0.f);
      if (n < N) v = *(const float4*)&g[(size_t)n * 512 + k0 + c4 * 4];
      *(float4*)&gs[r][c4 * 4] = v;
    }
    __syncthreads();
#pragma unroll 4
    for (int kk4 = 0; kk4 < 32; ++kk4) {
      float w0 = ws[kk4 * 4 + 0][lane];
      float w1 = ws[kk4 * 4 + 1][lane];
      float w2 = ws[kk4 * 4 + 2][lane];
      float w3 = ws[kk4 * 4 + 3][lane];
#pragma unroll
      for (int r = 0; r < 16; ++r) {
        float4 gv = *(const float4*)&gs[w * 16 + r][kk4 * 4];
        acc[r] += gv.x * w0 + gv.y * w1 + gv.z * w2 + gv.w * w3;
      }
    }
  }
  float bb = b2[lane];
#pragma unroll
  for (int r = 0; r < 16; ++r) {
    int n = row0 + w * 16 + r;
    if (n < N) out[(size_t)n * 64 + lane] = acc[r] + bb;
  }
}

extern "C" void kernel_launch(void* const* d_in, const int* in_sizes, int n_in,
                              void* d_out, int out_size, void* d_ws, size_t ws_size,
                              hipStream_t stream) {
  const float* x     = (const float*)d_in[0];
  const void*  ei    = d_in[1];
  const float* W1    = (const float*)d_in[2];
  const float* attl1 = (const float*)d_in[3];
  const float* attr1 = (const float*)d_in[4];
  const float* b1    = (const float*)d_in[5];
  const float* W2    = (const float*)d_in[6];
  const float* attl2 = (const float*)d_in[7];
  const float* attr2 = (const float*)d_in[8];
  const float* b2    = (const float*)d_in[9];
  float* out = (float*)d_out;

  int N = in_sizes[0] / 128;
  int E = in_sizes[1] / 2;

  char* ws = (char*)d_ws;
  size_t off = 0;
  auto alloc = [&](size_t bytes) {
    char* p = ws + off;
    off += (bytes + 255) & ~size_t(255);
    return p;
  };
  int*   edges   = (int*)alloc((size_t)2 * E * 4);
  int*   flag    = (int*)alloc(256);
  int*   deg     = (int*)alloc((size_t)N * 4);
  int*   cursor  = (int*)alloc((size_t)N * 4);
  int*   rowptr  = (int*)alloc((size_t)(N + 1) * 4);
  int*   bsum    = (int*)alloc(1024);
  int*   boff    = (int*)alloc(1024);
  int*   csr_src = (int*)alloc((size_t)E * 4);
  float* xl1     = (float*)alloc((size_t)N * 64 * 4);
  float* a1      = (float*)alloc((size_t)N * 16 * 4);
  float* hr      = (float*)alloc((size_t)N * 64 * 4);
  float* a2      = (float*)alloc((size_t)N * 16 * 4);
  float* wl      = (float*)alloc(64 * 8 * 4);
  float* wr      = (float*)alloc(64 * 8 * 4);
  float* Wt2     = (float*)alloc(512 * 64 * 4);
  float* g       = (float*)alloc((size_t)N * 512 * 4);
  (void)ws_size;

  const int* srcp = edges;
  const int* dstp = edges + E;
  int SB = (N + 1 + NT - 1) / NT;   // must be <= 256

  detect_kernel<<<1, NT, 0, stream>>>((const int*)ei, flag, 2 * E);
  zero2_kernel<<<(N + NT - 1) / NT, NT, 0, stream>>>(deg, cursor, N);
  cvt_edges_kernel<<<(2 * E + NT - 1) / NT, NT, 0, stream>>>(ei, edges, flag, deg, E, 2 * E);

  // CSR build
  scan1_kernel<<<SB, NT, 0, stream>>>(deg, bsum, N);
  scan2_kernel<<<1, NT, 0, stream>>>(bsum, boff, SB);
  scan3_kernel<<<SB, NT, 0, stream>>>(deg, boff, rowptr, N);
  scatter_kernel<<<(E + NT - 1) / NT, NT, 0, stream>>>(srcp, dstp, rowptr, cursor, csr_src, E);

  // dense precomputation
  gemm1_kernel<<<(N + 15) / 16, NT, 0, stream>>>(x, W1, attl1, attr1, xl1, a1, N);
  foldw_kernel<<<1, 512, 0, stream>>>(W2, attl2, attr2, wl, wr);
  foldWt_kernel<<<(512 * 64 + NT - 1) / NT, NT, 0, stream>>>(W2, Wt2);

  // layer 1 aggregation (+ fused relu/bias + layer-2 attention dots)
  node_aggr1_kernel<<<(N + 3) / 4, NT, 0, stream>>>(rowptr, csr_src, a1, xl1, b1, wl, wr, hr, a2, N);

  // layer 2 aggregation -> g, then tiled GEMM epilogue
  node_aggr2_kernel<<<(N + 3) / 4, NT, 0, stream>>>(rowptr, csr_src, a2, hr, g, N);
  gemm3_kernel<<<(N + 63) / 64, NT, 0, stream>>>(g, Wt2, b2, out, N);
}

// Round 5
// 370.171 us; speedup vs baseline: 1.2684x; 1.2684x over previous
//
#include <hip/hip_runtime.h>
#include <stdint.h>

#define NT 256

__device__ __forceinline__ float lrelu(float x) { return x > 0.f ? x : 0.2f * x; }

// ---- edge dtype detection (int32 vs int64) ----
__global__ void detect_kernel(const int* __restrict__ ei, int* __restrict__ flag, int twoE) {
  __shared__ int any;
  if (threadIdx.x == 0) any = 0;
  __syncthreads();
  int n = twoE < 4096 ? twoE : 4096;
  for (int i = threadIdx.x * 2 + 1; i < n; i += 2 * NT)
    if (ei[i] != 0) any = 1;   // benign race, same value
  __syncthreads();
  if (threadIdx.x == 0) *flag = any;   // 1 -> int32 data, 0 -> int64
}

// ---- convert edges + fused dst histogram ----
__global__ void cvt_edges_kernel(const void* __restrict__ ei, int* __restrict__ out,
                                 const int* __restrict__ flag, int* __restrict__ deg,
                                 int E, int twoE) {
  int i = blockIdx.x * NT + threadIdx.x;
  if (i >= twoE) return;
  int v;
  if (*flag) v = ((const int*)ei)[i];
  else       v = (int)((const long long*)ei)[i];
  out[i] = v;
  if (i >= E) atomicAdd(&deg[v], 1);   // dst half
}

// ---- CSR build ----
__global__ void zero2_kernel(int* __restrict__ a, int* __restrict__ b, int n) {
  int i = blockIdx.x * NT + threadIdx.x;
  if (i < n) { a[i] = 0; b[i] = 0; }
}

__global__ void scan1_kernel(const int* __restrict__ deg, int* __restrict__ bsum, int N) {
  __shared__ int sm[NT];
  int idx = blockIdx.x * NT + threadIdx.x;
  sm[threadIdx.x] = (idx < N) ? deg[idx] : 0;
  __syncthreads();
  for (int s = NT / 2; s > 0; s >>= 1) {
    if (threadIdx.x < s) sm[threadIdx.x] += sm[threadIdx.x + s];
    __syncthreads();
  }
  if (threadIdx.x == 0) bsum[blockIdx.x] = sm[0];
}

__global__ void scan2_kernel(const int* __restrict__ bsum, int* __restrict__ boff, int SB) {
  __shared__ int sm[NT];
  int t = threadIdx.x;
  int v = (t < SB) ? bsum[t] : 0;
  sm[t] = v;
  __syncthreads();
  for (int s = 1; s < NT; s <<= 1) {
    int add = (t >= s) ? sm[t - s] : 0;
    __syncthreads();
    sm[t] += add;
    __syncthreads();
  }
  if (t < SB) boff[t] = sm[t] - v;   // exclusive
}

__global__ void scan3_kernel(const int* __restrict__ deg, const int* __restrict__ boff,
                             int* __restrict__ rowptr, int N) {
  __shared__ int sm[NT];
  int idx = blockIdx.x * NT + threadIdx.x;
  int v = (idx < N) ? deg[idx] : 0;
  sm[threadIdx.x] = v;
  __syncthreads();
  for (int s = 1; s < NT; s <<= 1) {
    int add = (threadIdx.x >= s) ? sm[threadIdx.x - s] : 0;
    __syncthreads();
    sm[threadIdx.x] += add;
    __syncthreads();
  }
  if (idx <= N) rowptr[idx] = boff[blockIdx.x] + sm[threadIdx.x] - v;  // exclusive scan
}

__global__ void scatter_kernel(const int* __restrict__ src, const int* __restrict__ dst,
                               const int* __restrict__ rowptr, int* __restrict__ cursor,
                               int* __restrict__ csr_src, int E) {
  int e = blockIdx.x * NT + threadIdx.x;
  if (e >= E) return;
  int d = dst[e];
  int pos = rowptr[d] + atomicAdd(&cursor[d], 1);
  csr_src[pos] = src[e];
}

// ---- layer 1 GEMM + attention dots: xl1 = x@W1, a1 = [a_l | a_r] ----
__global__ void __launch_bounds__(NT)
gemm1_kernel(const float* __restrict__ x, const float* __restrict__ W1,
             const float* __restrict__ attl, const float* __restrict__ attr,
             float* __restrict__ xl1, float* __restrict__ a1, int N) {
  __shared__ float Ws[128 * 64];
  __shared__ float xs[16][128];
  for (int i = threadIdx.x; i < 128 * 16; i += NT)     // float4 units of Ws
    *(float4*)&Ws[i * 4] = *(const float4*)&W1[i * 4];
  int row0 = blockIdx.x * 16;
  for (int i = threadIdx.x; i < 16 * 32; i += NT) {    // float4 units of xs
    int r = i >> 5, c4 = i & 31;
    int n = row0 + r;
    float4 v = make_float4(0.f, 0.f, 0.f, 0.f);
    if (n < N) v = *(const float4*)&x[(size_t)n * 128 + c4 * 4];
    *(float4*)&xs[r][c4 * 4] = v;
  }
  __syncthreads();
  int w = threadIdx.x >> 6;
  int lane = threadIdx.x & 63;
  float al = attl[lane], ar = attr[lane];
  for (int rr = 0; rr < 4; ++rr) {
    int n = row0 + w * 4 + rr;
    if (n >= N) break;
    float acc = 0.f;
#pragma unroll 8
    for (int k = 0; k < 128; ++k) acc += xs[w * 4 + rr][k] * Ws[k * 64 + lane];
    xl1[(size_t)n * 64 + lane] = acc;
    float pl = acc * al;
    float pr = acc * ar;
#pragma unroll
    for (int m = 1; m < 8; m <<= 1) {
      pl += __shfl_xor(pl, m, 64);
      pr += __shfl_xor(pr, m, 64);
    }
    if ((lane & 7) == 0) {
      int h = lane >> 3;
      a1[n * 16 + h] = pl;
      a1[n * 16 + 8 + h] = pr;
    }
  }
}

// ---- fold W2 with att vectors: wl[k][h] = sum_f W2[k, h*64+f]*attl2[h,f] ----
__global__ void foldw_kernel(const float* __restrict__ W2, const float* __restrict__ attl2,
                             const float* __restrict__ attr2, float* __restrict__ wl,
                             float* __restrict__ wr) {
  int t = threadIdx.x;           // 0..511
  int k = t >> 3, h = t & 7;
  float sl = 0.f, sr = 0.f;
  for (int f = 0; f < 64; ++f) {
    float w = W2[k * 512 + h * 64 + f];
    sl += w * attl2[h * 64 + f];
    sr += w * attr2[h * 64 + f];
  }
  wl[k * 8 + h] = sl;
  wr[k * 8 + h] = sr;
}

// ---- Wt2[hk][f] = W2[k, h*64+f] * 0.125  (coalesced over f) ----
__global__ void foldWt_kernel(const float* __restrict__ W2, float* __restrict__ Wt2) {
  int idx = blockIdx.x * NT + threadIdx.x;   // over 512*64
  if (idx >= 512 * 64) return;
  int f = idx & 63;
  int hk = idx >> 6;           // h*64+k
  int h = hk >> 6, k = hk & 63;
  Wt2[idx] = W2[k * 512 + h * 64 + f] * 0.125f;
}

// ---- layer1: single-pass softmax+aggregation, LDS-staged edge weights ----
__global__ void __launch_bounds__(NT)
node_aggr1_kernel(const int* __restrict__ rowptr, const int* __restrict__ csr_src,
                  const float* __restrict__ a1, const float* __restrict__ xl1,
                  const float* __restrict__ b1, const float* __restrict__ wl,
                  const float* __restrict__ wr, float* __restrict__ hr,
                  float* __restrict__ a2, int N) {
  __shared__ float ps[4][64][8];
  __shared__ int ss[4][64];
  int w = threadIdx.x >> 6;
  int n = blockIdx.x * 4 + w;
  if (n >= N) return;
  int lane = threadIdx.x & 63;
  int hown = lane >> 3;
  int base = rowptr[n];
  int deg = rowptr[n + 1] - base;

  float4 r0 = *(const float4*)(a1 + n * 16 + 8);
  float4 r1 = *(const float4*)(a1 + n * 16 + 12);
  float ar[8] = {r0.x, r0.y, r0.z, r0.w, r1.x, r1.y, r1.z, r1.w};

  float acc = 0.f;
  float dnl[8] = {0.f, 0.f, 0.f, 0.f, 0.f, 0.f, 0.f, 0.f};

  for (int j0 = 0; j0 < deg; j0 += 64) {
    int cnt = deg - j0; if (cnt > 64) cnt = 64;
    if (lane < cnt) {
      int s = csr_src[base + j0 + lane];
      ss[w][lane] = s;
      float4 l0 = *(const float4*)(a1 + s * 16);
      float4 l1 = *(const float4*)(a1 + s * 16 + 4);
      float p0 = __expf(lrelu(l0.x + ar[0]));
      float p1 = __expf(lrelu(l0.y + ar[1]));
      float p2 = __expf(lrelu(l0.z + ar[2]));
      float p3 = __expf(lrelu(l0.w + ar[3]));
      float p4 = __expf(lrelu(l1.x + ar[4]));
      float p5 = __expf(lrelu(l1.y + ar[5]));
      float p6 = __expf(lrelu(l1.z + ar[6]));
      float p7 = __expf(lrelu(l1.w + ar[7]));
      dnl[0] += p0; dnl[1] += p1; dnl[2] += p2; dnl[3] += p3;
      dnl[4] += p4; dnl[5] += p5; dnl[6] += p6; dnl[7] += p7;
      *(float4*)&ps[w][lane][0] = make_float4(p0, p1, p2, p3);
      *(float4*)&ps[w][lane][4] = make_float4(p4, p5, p6, p7);
    }
    asm volatile("s_waitcnt lgkmcnt(0)" ::: "memory");
    for (int j = 0; j < cnt; ++j) {
      int s = ss[w][j];
      float p = ps[w][j][hown];
      acc += p * xl1[(size_t)s * 64 + lane];
    }
  }
#pragma unroll
  for (int m = 1; m < 64; m <<= 1) {
#pragma unroll
    for (int h = 0; h < 8; ++h) dnl[h] += __shfl_xor(dnl[h], m, 64);
  }
  float dnh = dnl[0];
#pragma unroll
  for (int h = 1; h < 8; ++h) if (hown == h) dnh = dnl[h];

  acc = acc / (dnh + 1e-16f);
  float hv = fmaxf(acc + b1[lane], 0.f);   // relu(out1 + b1)
  hr[(size_t)n * 64 + lane] = hv;

  // layer-2 attention dots
  float tl[8], tr[8];
#pragma unroll
  for (int h2 = 0; h2 < 8; ++h2) { tl[h2] = hv * wl[lane * 8 + h2]; tr[h2] = hv * wr[lane * 8 + h2]; }
#pragma unroll
  for (int m = 1; m < 64; m <<= 1) {
#pragma unroll
    for (int h2 = 0; h2 < 8; ++h2) { tl[h2] += __shfl_xor(tl[h2], m, 64); tr[h2] += __shfl_xor(tr[h2], m, 64); }
  }
  if (lane == 0) {
#pragma unroll
    for (int h2 = 0; h2 < 8; ++h2) {
      a2[n * 16 + h2] = tl[h2];
      a2[n * 16 + 8 + h2] = tr[h2];
    }
  }
}

// ---- layer2: single-pass softmax+aggregation -> normalized g[n,512] ----
__global__ void __launch_bounds__(NT)
node_aggr2_kernel(const int* __restrict__ rowptr, const int* __restrict__ csr_src,
                  const float* __restrict__ a2, const float* __restrict__ hr,
                  float* __restrict__ g, int N) {
  __shared__ float ps[4][64][8];
  __shared__ int ss[4][64];
  int w = threadIdx.x >> 6;
  int n = blockIdx.x * 4 + w;
  if (n >= N) return;
  int lane = threadIdx.x & 63;
  int base = rowptr[n];
  int deg = rowptr[n + 1] - base;

  float4 r0 = *(const float4*)(a2 + n * 16 + 8);
  float4 r1 = *(const float4*)(a2 + n * 16 + 12);
  float ar[8] = {r0.x, r0.y, r0.z, r0.w, r1.x, r1.y, r1.z, r1.w};

  float acc[8] = {0.f, 0.f, 0.f, 0.f, 0.f, 0.f, 0.f, 0.f};
  float dnl[8] = {0.f, 0.f, 0.f, 0.f, 0.f, 0.f, 0.f, 0.f};

  for (int j0 = 0; j0 < deg; j0 += 64) {
    int cnt = deg - j0; if (cnt > 64) cnt = 64;
    if (lane < cnt) {
      int s = csr_src[base + j0 + lane];
      ss[w][lane] = s;
      float4 l0 = *(const float4*)(a2 + s * 16);
      float4 l1 = *(const float4*)(a2 + s * 16 + 4);
      float p0 = __expf(lrelu(l0.x + ar[0]));
      float p1 = __expf(lrelu(l0.y + ar[1]));
      float p2 = __expf(lrelu(l0.z + ar[2]));
      float p3 = __expf(lrelu(l0.w + ar[3]));
      float p4 = __expf(lrelu(l1.x + ar[4]));
      float p5 = __expf(lrelu(l1.y + ar[5]));
      float p6 = __expf(lrelu(l1.z + ar[6]));
      float p7 = __expf(lrelu(l1.w + ar[7]));
      dnl[0] += p0; dnl[1] += p1; dnl[2] += p2; dnl[3] += p3;
      dnl[4] += p4; dnl[5] += p5; dnl[6] += p6; dnl[7] += p7;
      *(float4*)&ps[w][lane][0] = make_float4(p0, p1, p2, p3);
      *(float4*)&ps[w][lane][4] = make_float4(p4, p5, p6, p7);
    }
    asm volatile("s_waitcnt lgkmcnt(0)" ::: "memory");
    for (int j = 0; j < cnt; ++j) {
      int s = ss[w][j];
      float hv = hr[(size_t)s * 64 + lane];
      float4 pa = *(const float4*)&ps[w][j][0];
      float4 pb = *(const float4*)&ps[w][j][4];
      acc[0] += pa.x * hv; acc[1] += pa.y * hv; acc[2] += pa.z * hv; acc[3] += pa.w * hv;
      acc[4] += pb.x * hv; acc[5] += pb.y * hv; acc[6] += pb.z * hv; acc[7] += pb.w * hv;
    }
  }
#pragma unroll
  for (int m = 1; m < 64; m <<= 1) {
#pragma unroll
    for (int h = 0; h < 8; ++h) dnl[h] += __shfl_xor(dnl[h], m, 64);
  }
#pragma unroll
  for (int h = 0; h < 8; ++h) {
    float v = acc[h] * (1.f / (dnl[h] + 1e-16f));
    g[(size_t)n * 512 + h * 64 + lane] = v;
  }
}

// ---- register-blocked fp32 GEMM: out[N,64] = g[N,512] @ Wt2[512,64] + b2 ----
// 128 rows/block; thread tile 4 rows x 8 cols; g staged TRANSPOSED in LDS.
#define G3R 128
__global__ void __launch_bounds__(NT)
gemm3_kernel(const float* __restrict__ g, const float* __restrict__ Wt2,
             const float* __restrict__ b2, float* __restrict__ out, int N) {
  __shared__ float gsT[32][G3R + 4];   // [k][row], padded
  __shared__ float wsk[32][64];        // [k][f]
  int row0 = blockIdx.x * G3R;
  int tid = threadIdx.x;
  int cg = (tid & 7) * 8;      // col base (8 cols)
  int rg = (tid >> 3) * 4;     // row base within block (4 rows)
  float acc[4][8];
#pragma unroll
  for (int r = 0; r < 4; ++r)
#pragma unroll
    for (int c = 0; c < 8; ++c) acc[r][c] = 0.f;

  for (int k0 = 0; k0 < 512; k0 += 32) {
    __syncthreads();
    // stage Wt2 chunk: 32x64 floats = 512 float4
    for (int i = tid; i < 512; i += NT)
      *(float4*)&wsk[i >> 4][(i & 15) * 4] =
          *(const float4*)&Wt2[(size_t)(k0 + (i >> 4)) * 64 + (i & 15) * 4];
    // stage g chunk transposed: 2 threads per row, 16 k each
    {
      int r = tid >> 1;
      int n = row0 + r;
      int ko = (tid & 1) * 16;
      if (n < N) {
        const float4* gp = (const float4*)&g[(size_t)n * 512 + k0 + ko];
#pragma unroll
        for (int q = 0; q < 4; ++q) {
          float4 v = gp[q];
          gsT[ko + q * 4 + 0][r] = v.x;
          gsT[ko + q * 4 + 1][r] = v.y;
          gsT[ko + q * 4 + 2][r] = v.z;
          gsT[ko + q * 4 + 3][r] = v.w;
        }
      } else {
#pragma unroll
        for (int q = 0; q < 16; ++q) gsT[ko + q][r] = 0.f;
      }
    }
    __syncthreads();
#pragma unroll
    for (int k = 0; k < 32; ++k) {
      float gv[4], wv[8];
      *(float4*)&gv[0] = *(const float4*)&gsT[k][rg];
      *(float4*)&wv[0] = *(const float4*)&wsk[k][cg];
      *(float4*)&wv[4] = *(const float4*)&wsk[k][cg + 4];
#pragma unroll
      for (int r = 0; r < 4; ++r)
#pragma unroll
        for (int c = 0; c < 8; ++c) acc[r][c] += gv[r] * wv[c];
    }
  }
  float bv[8];
#pragma unroll
  for (int c = 0; c < 8; ++c) bv[c] = b2[cg + c];
#pragma unroll
  for (int r = 0; r < 4; ++r) {
    int n = row0 + rg + r;
    if (n < N) {
      float4 o0 = make_float4(acc[r][0] + bv[0], acc[r][1] + bv[1],
                              acc[r][2] + bv[2], acc[r][3] + bv[3]);
      float4 o1 = make_float4(acc[r][4] + bv[4], acc[r][5] + bv[5],
                              acc[r][6] + bv[6], acc[r][7] + bv[7]);
      *(float4*)&out[(size_t)n * 64 + cg] = o0;
      *(float4*)&out[(size_t)n * 64 + cg + 4] = o1;
    }
  }
}

extern "C" void kernel_launch(void* const* d_in, const int* in_sizes, int n_in,
                              void* d_out, int out_size, void* d_ws, size_t ws_size,
                              hipStream_t stream) {
  const float* x     = (const float*)d_in[0];
  const void*  ei    = d_in[1];
  const float* W1    = (const float*)d_in[2];
  const float* attl1 = (const float*)d_in[3];
  const float* attr1 = (const float*)d_in[4];
  const float* b1    = (const float*)d_in[5];
  const float* W2    = (const float*)d_in[6];
  const float* attl2 = (const float*)d_in[7];
  const float* attr2 = (const float*)d_in[8];
  const float* b2    = (const float*)d_in[9];
  float* out = (float*)d_out;

  int N = in_sizes[0] / 128;
  int E = in_sizes[1] / 2;

  char* ws = (char*)d_ws;
  size_t off = 0;
  auto alloc = [&](size_t bytes) {
    char* p = ws + off;
    off += (bytes + 255) & ~size_t(255);
    return p;
  };
  int*   edges   = (int*)alloc((size_t)2 * E * 4);
  int*   flag    = (int*)alloc(256);
  int*   deg     = (int*)alloc((size_t)N * 4);
  int*   cursor  = (int*)alloc((size_t)N * 4);
  int*   rowptr  = (int*)alloc((size_t)(N + 1) * 4);
  int*   bsum    = (int*)alloc(1024);
  int*   boff    = (int*)alloc(1024);
  int*   csr_src = (int*)alloc((size_t)E * 4);
  float* xl1     = (float*)alloc((size_t)N * 64 * 4);
  float* a1      = (float*)alloc((size_t)N * 16 * 4);
  float* hr      = (float*)alloc((size_t)N * 64 * 4);
  float* a2      = (float*)alloc((size_t)N * 16 * 4);
  float* wl      = (float*)alloc(64 * 8 * 4);
  float* wr      = (float*)alloc(64 * 8 * 4);
  float* Wt2     = (float*)alloc(512 * 64 * 4);
  float* g       = (float*)alloc((size_t)N * 512 * 4);
  (void)ws_size;

  const int* srcp = edges;
  const int* dstp = edges + E;
  int SB = (N + 1 + NT - 1) / NT;   // must be <= 256

  detect_kernel<<<1, NT, 0, stream>>>((const int*)ei, flag, 2 * E);
  zero2_kernel<<<(N + NT - 1) / NT, NT, 0, stream>>>(deg, cursor, N);
  cvt_edges_kernel<<<(2 * E + NT - 1) / NT, NT, 0, stream>>>(ei, edges, flag, deg, E, 2 * E);

  // CSR build
  scan1_kernel<<<SB, NT, 0, stream>>>(deg, bsum, N);
  scan2_kernel<<<1, NT, 0, stream>>>(bsum, boff, SB);
  scan3_kernel<<<SB, NT, 0, stream>>>(deg, boff, rowptr, N);
  scatter_kernel<<<(E + NT - 1) / NT, NT, 0, stream>>>(srcp, dstp, rowptr, cursor, csr_src, E);

  // dense precomputation
  gemm1_kernel<<<(N + 15) / 16, NT, 0, stream>>>(x, W1, attl1, attr1, xl1, a1, N);
  foldw_kernel<<<1, 512, 0, stream>>>(W2, attl2, attr2, wl, wr);
  foldWt_kernel<<<(512 * 64 + NT - 1) / NT, NT, 0, stream>>>(W2, Wt2);

  // layer 1 aggregation (+ fused relu/bias + layer-2 attention dots)
  node_aggr1_kernel<<<(N + 3) / 4, NT, 0, stream>>>(rowptr, csr_src, a1, xl1, b1, wl, wr, hr, a2, N);

  // layer 2 aggregation -> g, then register-blocked GEMM epilogue
  node_aggr2_kernel<<<(N + 3) / 4, NT, 0, stream>>>(rowptr, csr_src, a2, hr, g, N);
  gemm3_kernel<<<(N + G3R - 1) / G3R, NT, 0, stream>>>(g, Wt2, b2, out, N);
}

// Round 6
// 365.251 us; speedup vs baseline: 1.2855x; 1.0135x over previous
//
#include <hip/hip_runtime.h>
#include <stdint.h>

#define NT 256

__device__ __forceinline__ float lrelu(float x) { return x > 0.f ? x : 0.2f * x; }

// ---- edge dtype detection (int32 vs int64) ----
__global__ void detect_kernel(const int* __restrict__ ei, int* __restrict__ flag, int twoE) {
  __shared__ int any;
  if (threadIdx.x == 0) any = 0;
  __syncthreads();
  int n = twoE < 4096 ? twoE : 4096;
  for (int i = threadIdx.x * 2 + 1; i < n; i += 2 * NT)
    if (ei[i] != 0) any = 1;   // benign race, same value
  __syncthreads();
  if (threadIdx.x == 0) *flag = any;   // 1 -> int32 data, 0 -> int64
}

// ---- convert edges + fused dst histogram ----
__global__ void cvt_edges_kernel(const void* __restrict__ ei, int* __restrict__ out,
                                 const int* __restrict__ flag, int* __restrict__ deg,
                                 int E, int twoE) {
  int i = blockIdx.x * NT + threadIdx.x;
  if (i >= twoE) return;
  int v;
  if (*flag) v = ((const int*)ei)[i];
  else       v = (int)((const long long*)ei)[i];
  out[i] = v;
  if (i >= E) atomicAdd(&deg[v], 1);   // dst half
}

// ---- CSR build ----
__global__ void zero2_kernel(int* __restrict__ a, int* __restrict__ b, int n) {
  int i = blockIdx.x * NT + threadIdx.x;
  if (i < n) { a[i] = 0; b[i] = 0; }
}

__global__ void scan1_kernel(const int* __restrict__ deg, int* __restrict__ bsum, int N) {
  __shared__ int sm[NT];
  int idx = blockIdx.x * NT + threadIdx.x;
  sm[threadIdx.x] = (idx < N) ? deg[idx] : 0;
  __syncthreads();
  for (int s = NT / 2; s > 0; s >>= 1) {
    if (threadIdx.x < s) sm[threadIdx.x] += sm[threadIdx.x + s];
    __syncthreads();
  }
  if (threadIdx.x == 0) bsum[blockIdx.x] = sm[0];
}

__global__ void scan2_kernel(const int* __restrict__ bsum, int* __restrict__ boff, int SB) {
  __shared__ int sm[NT];
  int t = threadIdx.x;
  int v = (t < SB) ? bsum[t] : 0;
  sm[t] = v;
  __syncthreads();
  for (int s = 1; s < NT; s <<= 1) {
    int add = (t >= s) ? sm[t - s] : 0;
    __syncthreads();
    sm[t] += add;
    __syncthreads();
  }
  if (t < SB) boff[t] = sm[t] - v;   // exclusive
}

__global__ void scan3_kernel(const int* __restrict__ deg, const int* __restrict__ boff,
                             int* __restrict__ rowptr, int N) {
  __shared__ int sm[NT];
  int idx = blockIdx.x * NT + threadIdx.x;
  int v = (idx < N) ? deg[idx] : 0;
  sm[threadIdx.x] = v;
  __syncthreads();
  for (int s = 1; s < NT; s <<= 1) {
    int add = (threadIdx.x >= s) ? sm[threadIdx.x - s] : 0;
    __syncthreads();
    sm[threadIdx.x] += add;
    __syncthreads();
  }
  if (idx <= N) rowptr[idx] = boff[blockIdx.x] + sm[threadIdx.x] - v;  // exclusive scan
}

__global__ void scatter_kernel(const int* __restrict__ src, const int* __restrict__ dst,
                               const int* __restrict__ rowptr, int* __restrict__ cursor,
                               int* __restrict__ csr_src, int E) {
  int e = blockIdx.x * NT + threadIdx.x;
  if (e >= E) return;
  int d = dst[e];
  int pos = rowptr[d] + atomicAdd(&cursor[d], 1);
  csr_src[pos] = src[e];
}

// ---- layer 1 GEMM + attention dots: xl1 = x@W1, a1 = [a_l | a_r] ----
// 32 rows/block
__global__ void __launch_bounds__(NT)
gemm1_kernel(const float* __restrict__ x, const float* __restrict__ W1,
             const float* __restrict__ attl, const float* __restrict__ attr,
             float* __restrict__ xl1, float* __restrict__ a1, int N) {
  __shared__ float Ws[128 * 64];
  __shared__ float xs[32][128];
  for (int i = threadIdx.x; i < 128 * 16; i += NT)     // float4 units of Ws
    *(float4*)&Ws[i * 4] = *(const float4*)&W1[i * 4];
  int row0 = blockIdx.x * 32;
  for (int i = threadIdx.x; i < 32 * 32; i += NT) {    // float4 units of xs
    int r = i >> 5, c4 = i & 31;
    int n = row0 + r;
    float4 v = make_float4(0.f, 0.f, 0.f, 0.f);
    if (n < N) v = *(const float4*)&x[(size_t)n * 128 + c4 * 4];
    *(float4*)&xs[r][c4 * 4] = v;
  }
  __syncthreads();
  int w = threadIdx.x >> 6;
  int lane = threadIdx.x & 63;
  float al = attl[lane], ar = attr[lane];
  for (int rr = 0; rr < 8; ++rr) {
    int n = row0 + w * 8 + rr;
    if (n >= N) break;
    float acc = 0.f;
#pragma unroll 8
    for (int k = 0; k < 128; ++k) acc += xs[w * 8 + rr][k] * Ws[k * 64 + lane];
    xl1[(size_t)n * 64 + lane] = acc;
    float pl = acc * al;
    float pr = acc * ar;
#pragma unroll
    for (int m = 1; m < 8; m <<= 1) {
      pl += __shfl_xor(pl, m, 64);
      pr += __shfl_xor(pr, m, 64);
    }
    if ((lane & 7) == 0) {
      int h = lane >> 3;
      a1[n * 16 + h] = pl;
      a1[n * 16 + 8 + h] = pr;
    }
  }
}

// ---- fold W2 with att vectors: wl[k][h] = sum_f W2[k, h*64+f]*attl2[h,f] ----
__global__ void foldw_kernel(const float* __restrict__ W2, const float* __restrict__ attl2,
                             const float* __restrict__ attr2, float* __restrict__ wl,
                             float* __restrict__ wr) {
  int t = threadIdx.x;           // 0..511
  int k = t >> 3, h = t & 7;
  float sl = 0.f, sr = 0.f;
  for (int f = 0; f < 64; ++f) {
    float w = W2[k * 512 + h * 64 + f];
    sl += w * attl2[h * 64 + f];
    sr += w * attr2[h * 64 + f];
  }
  wl[k * 8 + h] = sl;
  wr[k * 8 + h] = sr;
}

// ---- Wt2[hk][f] = W2[k, h*64+f] * 0.125  (coalesced over f) ----
__global__ void foldWt_kernel(const float* __restrict__ W2, float* __restrict__ Wt2) {
  int idx = blockIdx.x * NT + threadIdx.x;   // over 512*64
  if (idx >= 512 * 64) return;
  int f = idx & 63;
  int hk = idx >> 6;           // h*64+k
  int h = hk >> 6, k = hk & 63;
  Wt2[idx] = W2[k * 512 + h * 64 + f] * 0.125f;
}

// ---- layer1: single-pass softmax+aggregation, LDS-staged edge weights ----
__global__ void __launch_bounds__(NT)
node_aggr1_kernel(const int* __restrict__ rowptr, const int* __restrict__ csr_src,
                  const float* __restrict__ a1, const float* __restrict__ xl1,
                  const float* __restrict__ b1, const float* __restrict__ wl,
                  const float* __restrict__ wr, float* __restrict__ hr,
                  float* __restrict__ a2, int N) {
  __shared__ float ps[4][64][8];
  __shared__ int ss[4][64];
  int w = threadIdx.x >> 6;
  int n = blockIdx.x * 4 + w;
  if (n >= N) return;
  int lane = threadIdx.x & 63;
  int hown = lane >> 3;
  int base = rowptr[n];
  int deg = rowptr[n + 1] - base;

  float4 r0 = *(const float4*)(a1 + n * 16 + 8);
  float4 r1 = *(const float4*)(a1 + n * 16 + 12);
  float ar[8] = {r0.x, r0.y, r0.z, r0.w, r1.x, r1.y, r1.z, r1.w};

  const float* xp = xl1 + lane;
  float acc = 0.f;
  float dnl[8] = {0.f, 0.f, 0.f, 0.f, 0.f, 0.f, 0.f, 0.f};

  for (int j0 = 0; j0 < deg; j0 += 64) {
    int cnt = deg - j0; if (cnt > 64) cnt = 64;
    if (lane < cnt) {
      int s = csr_src[base + j0 + lane];
      ss[w][lane] = s;
      float4 l0 = *(const float4*)(a1 + s * 16);
      float4 l1 = *(const float4*)(a1 + s * 16 + 4);
      float p0 = __expf(lrelu(l0.x + ar[0]));
      float p1 = __expf(lrelu(l0.y + ar[1]));
      float p2 = __expf(lrelu(l0.z + ar[2]));
      float p3 = __expf(lrelu(l0.w + ar[3]));
      float p4 = __expf(lrelu(l1.x + ar[4]));
      float p5 = __expf(lrelu(l1.y + ar[5]));
      float p6 = __expf(lrelu(l1.z + ar[6]));
      float p7 = __expf(lrelu(l1.w + ar[7]));
      dnl[0] += p0; dnl[1] += p1; dnl[2] += p2; dnl[3] += p3;
      dnl[4] += p4; dnl[5] += p5; dnl[6] += p6; dnl[7] += p7;
      *(float4*)&ps[w][lane][0] = make_float4(p0, p1, p2, p3);
      *(float4*)&ps[w][lane][4] = make_float4(p4, p5, p6, p7);
    }
    asm volatile("s_waitcnt lgkmcnt(0)" ::: "memory");
    int j = 0;
    for (; j + 8 <= cnt; j += 8) {
      int s0 = ss[w][j+0], s1 = ss[w][j+1], s2 = ss[w][j+2], s3 = ss[w][j+3];
      int s4 = ss[w][j+4], s5 = ss[w][j+5], s6 = ss[w][j+6], s7 = ss[w][j+7];
      float q0 = ps[w][j+0][hown], q1 = ps[w][j+1][hown];
      float q2 = ps[w][j+2][hown], q3 = ps[w][j+3][hown];
      float q4 = ps[w][j+4][hown], q5 = ps[w][j+5][hown];
      float q6 = ps[w][j+6][hown], q7 = ps[w][j+7][hown];
      float v0 = xp[(size_t)s0 * 64], v1 = xp[(size_t)s1 * 64];
      float v2 = xp[(size_t)s2 * 64], v3 = xp[(size_t)s3 * 64];
      float v4 = xp[(size_t)s4 * 64], v5 = xp[(size_t)s5 * 64];
      float v6 = xp[(size_t)s6 * 64], v7 = xp[(size_t)s7 * 64];
      acc += q0*v0 + q1*v1 + q2*v2 + q3*v3 + q4*v4 + q5*v5 + q6*v6 + q7*v7;
    }
    for (; j < cnt; ++j) {
      int s = ss[w][j];
      acc += ps[w][j][hown] * xp[(size_t)s * 64];
    }
  }
#pragma unroll
  for (int m = 1; m < 64; m <<= 1) {
#pragma unroll
    for (int h = 0; h < 8; ++h) dnl[h] += __shfl_xor(dnl[h], m, 64);
  }
  float dnh = dnl[0];
#pragma unroll
  for (int h = 1; h < 8; ++h) if (hown == h) dnh = dnl[h];

  acc = acc / (dnh + 1e-16f);
  float hv = fmaxf(acc + b1[lane], 0.f);   // relu(out1 + b1)
  hr[(size_t)n * 64 + lane] = hv;

  // layer-2 attention dots
  float tl[8], tr[8];
#pragma unroll
  for (int h2 = 0; h2 < 8; ++h2) { tl[h2] = hv * wl[lane * 8 + h2]; tr[h2] = hv * wr[lane * 8 + h2]; }
#pragma unroll
  for (int m = 1; m < 64; m <<= 1) {
#pragma unroll
    for (int h2 = 0; h2 < 8; ++h2) { tl[h2] += __shfl_xor(tl[h2], m, 64); tr[h2] += __shfl_xor(tr[h2], m, 64); }
  }
  if (lane == 0) {
#pragma unroll
    for (int h2 = 0; h2 < 8; ++h2) {
      a2[n * 16 + h2] = tl[h2];
      a2[n * 16 + 8 + h2] = tr[h2];
    }
  }
}

// ---- layer2: single-pass softmax+aggregation -> normalized g[n,512] ----
__global__ void __launch_bounds__(NT)
node_aggr2_kernel(const int* __restrict__ rowptr, const int* __restrict__ csr_src,
                  const float* __restrict__ a2, const float* __restrict__ hr,
                  float* __restrict__ g, int N) {
  __shared__ float ps[4][64][8];
  __shared__ int ss[4][64];
  int w = threadIdx.x >> 6;
  int n = blockIdx.x * 4 + w;
  if (n >= N) return;
  int lane = threadIdx.x & 63;
  int base = rowptr[n];
  int deg = rowptr[n + 1] - base;

  float4 r0 = *(const float4*)(a2 + n * 16 + 8);
  float4 r1 = *(const float4*)(a2 + n * 16 + 12);
  float ar[8] = {r0.x, r0.y, r0.z, r0.w, r1.x, r1.y, r1.z, r1.w};

  const float* hp = hr + lane;
  float acc[8] = {0.f, 0.f, 0.f, 0.f, 0.f, 0.f, 0.f, 0.f};
  float dnl[8] = {0.f, 0.f, 0.f, 0.f, 0.f, 0.f, 0.f, 0.f};

  for (int j0 = 0; j0 < deg; j0 += 64) {
    int cnt = deg - j0; if (cnt > 64) cnt = 64;
    if (lane < cnt) {
      int s = csr_src[base + j0 + lane];
      ss[w][lane] = s;
      float4 l0 = *(const float4*)(a2 + s * 16);
      float4 l1 = *(const float4*)(a2 + s * 16 + 4);
      float p0 = __expf(lrelu(l0.x + ar[0]));
      float p1 = __expf(lrelu(l0.y + ar[1]));
      float p2 = __expf(lrelu(l0.z + ar[2]));
      float p3 = __expf(lrelu(l0.w + ar[3]));
      float p4 = __expf(lrelu(l1.x + ar[4]));
      float p5 = __expf(lrelu(l1.y + ar[5]));
      float p6 = __expf(lrelu(l1.z + ar[6]));
      float p7 = __expf(lrelu(l1.w + ar[7]));
      dnl[0] += p0; dnl[1] += p1; dnl[2] += p2; dnl[3] += p3;
      dnl[4] += p4; dnl[5] += p5; dnl[6] += p6; dnl[7] += p7;
      *(float4*)&ps[w][lane][0] = make_float4(p0, p1, p2, p3);
      *(float4*)&ps[w][lane][4] = make_float4(p4, p5, p6, p7);
    }
    asm volatile("s_waitcnt lgkmcnt(0)" ::: "memory");
    int j = 0;
    for (; j + 4 <= cnt; j += 4) {
      int s0 = ss[w][j+0], s1 = ss[w][j+1], s2 = ss[w][j+2], s3 = ss[w][j+3];
      float v0 = hp[(size_t)s0 * 64], v1 = hp[(size_t)s1 * 64];
      float v2 = hp[(size_t)s2 * 64], v3 = hp[(size_t)s3 * 64];
      float4 pa0 = *(const float4*)&ps[w][j+0][0];
      float4 pb0 = *(const float4*)&ps[w][j+0][4];
      float4 pa1 = *(const float4*)&ps[w][j+1][0];
      float4 pb1 = *(const float4*)&ps[w][j+1][4];
      float4 pa2 = *(const float4*)&ps[w][j+2][0];
      float4 pb2 = *(const float4*)&ps[w][j+2][4];
      float4 pa3 = *(const float4*)&ps[w][j+3][0];
      float4 pb3 = *(const float4*)&ps[w][j+3][4];
      acc[0] += pa0.x*v0 + pa1.x*v1 + pa2.x*v2 + pa3.x*v3;
      acc[1] += pa0.y*v0 + pa1.y*v1 + pa2.y*v2 + pa3.y*v3;
      acc[2] += pa0.z*v0 + pa1.z*v1 + pa2.z*v2 + pa3.z*v3;
      acc[3] += pa0.w*v0 + pa1.w*v1 + pa2.w*v2 + pa3.w*v3;
      acc[4] += pb0.x*v0 + pb1.x*v1 + pb2.x*v2 + pb3.x*v3;
      acc[5] += pb0.y*v0 + pb1.y*v1 + pb2.y*v2 + pb3.y*v3;
      acc[6] += pb0.z*v0 + pb1.z*v1 + pb2.z*v2 + pb3.z*v3;
      acc[7] += pb0.w*v0 + pb1.w*v1 + pb2.w*v2 + pb3.w*v3;
    }
    for (; j < cnt; ++j) {
      int s = ss[w][j];
      float hv = hp[(size_t)s * 64];
      float4 pa = *(const float4*)&ps[w][j][0];
      float4 pb = *(const float4*)&ps[w][j][4];
      acc[0] += pa.x * hv; acc[1] += pa.y * hv; acc[2] += pa.z * hv; acc[3] += pa.w * hv;
      acc[4] += pb.x * hv; acc[5] += pb.y * hv; acc[6] += pb.z * hv; acc[7] += pb.w * hv;
    }
  }
#pragma unroll
  for (int m = 1; m < 64; m <<= 1) {
#pragma unroll
    for (int h = 0; h < 8; ++h) dnl[h] += __shfl_xor(dnl[h], m, 64);
  }
#pragma unroll
  for (int h = 0; h < 8; ++h) {
    float v = acc[h] * (1.f / (dnl[h] + 1e-16f));
    g[(size_t)n * 512 + h * 64 + lane] = v;
  }
}

// ---- register-blocked fp32 GEMM: out[N,64] = g[N,512] @ Wt2[512,64] + b2 ----
#define G3R 128
__global__ void __launch_bounds__(NT)
gemm3_kernel(const float* __restrict__ g, const float* __restrict__ Wt2,
             const float* __restrict__ b2, float* __restrict__ out, int N) {
  __shared__ float gsT[32][G3R + 4];   // [k][row], padded
  __shared__ float wsk[32][64];        // [k][f]
  int row0 = blockIdx.x * G3R;
  int tid = threadIdx.x;
  int cg = (tid & 7) * 8;      // col base (8 cols)
  int rg = (tid >> 3) * 4;     // row base within block (4 rows)
  float acc[4][8];
#pragma unroll
  for (int r = 0; r < 4; ++r)
#pragma unroll
    for (int c = 0; c < 8; ++c) acc[r][c] = 0.f;

  for (int k0 = 0; k0 < 512; k0 += 32) {
    __syncthreads();
    for (int i = tid; i < 512; i += NT)
      *(float4*)&wsk[i >> 4][(i & 15) * 4] =
          *(const float4*)&Wt2[(size_t)(k0 + (i >> 4)) * 64 + (i & 15) * 4];
    {
      int r = tid >> 1;
      int n = row0 + r;
      int ko = (tid & 1) * 16;
      if (n < N) {
        const float4* gp = (const float4*)&g[(size_t)n * 512 + k0 + ko];
#pragma unroll
        for (int q = 0; q < 4; ++q) {
          float4 v = gp[q];
          gsT[ko + q * 4 + 0][r] = v.x;
          gsT[ko + q * 4 + 1][r] = v.y;
          gsT[ko + q * 4 + 2][r] = v.z;
          gsT[ko + q * 4 + 3][r] = v.w;
        }
      } else {
#pragma unroll
        for (int q = 0; q < 16; ++q) gsT[ko + q][r] = 0.f;
      }
    }
    __syncthreads();
#pragma unroll
    for (int k = 0; k < 32; ++k) {
      float gv[4], wv[8];
      *(float4*)&gv[0] = *(const float4*)&gsT[k][rg];
      *(float4*)&wv[0] = *(const float4*)&wsk[k][cg];
      *(float4*)&wv[4] = *(const float4*)&wsk[k][cg + 4];
#pragma unroll
      for (int r = 0; r < 4; ++r)
#pragma unroll
        for (int c = 0; c < 8; ++c) acc[r][c] += gv[r] * wv[c];
    }
  }
  float bv[8];
#pragma unroll
  for (int c = 0; c < 8; ++c) bv[c] = b2[cg + c];
#pragma unroll
  for (int r = 0; r < 4; ++r) {
    int n = row0 + rg + r;
    if (n < N) {
      float4 o0 = make_float4(acc[r][0] + bv[0], acc[r][1] + bv[1],
                              acc[r][2] + bv[2], acc[r][3] + bv[3]);
      float4 o1 = make_float4(acc[r][4] + bv[4], acc[r][5] + bv[5],
                              acc[r][6] + bv[6], acc[r][7] + bv[7]);
      *(float4*)&out[(size_t)n * 64 + cg] = o0;
      *(float4*)&out[(size_t)n * 64 + cg + 4] = o1;
    }
  }
}

extern "C" void kernel_launch(void* const* d_in, const int* in_sizes, int n_in,
                              void* d_out, int out_size, void* d_ws, size_t ws_size,
                              hipStream_t stream) {
  const float* x     = (const float*)d_in[0];
  const void*  ei    = d_in[1];
  const float* W1    = (const float*)d_in[2];
  const float* attl1 = (const float*)d_in[3];
  const float* attr1 = (const float*)d_in[4];
  const float* b1    = (const float*)d_in[5];
  const float* W2    = (const float*)d_in[6];
  const float* attl2 = (const float*)d_in[7];
  const float* attr2 = (const float*)d_in[8];
  const float* b2    = (const float*)d_in[9];
  float* out = (float*)d_out;

  int N = in_sizes[0] / 128;
  int E = in_sizes[1] / 2;

  char* ws = (char*)d_ws;
  size_t off = 0;
  auto alloc = [&](size_t bytes) {
    char* p = ws + off;
    off += (bytes + 255) & ~size_t(255);
    return p;
  };
  int*   edges   = (int*)alloc((size_t)2 * E * 4);
  int*   flag    = (int*)alloc(256);
  int*   deg     = (int*)alloc((size_t)N * 4);
  int*   cursor  = (int*)alloc((size_t)N * 4);
  int*   rowptr  = (int*)alloc((size_t)(N + 1) * 4);
  int*   bsum    = (int*)alloc(1024);
  int*   boff    = (int*)alloc(1024);
  int*   csr_src = (int*)alloc((size_t)E * 4);
  float* xl1     = (float*)alloc((size_t)N * 64 * 4);
  float* a1      = (float*)alloc((size_t)N * 16 * 4);
  float* hr      = (float*)alloc((size_t)N * 64 * 4);
  float* a2      = (float*)alloc((size_t)N * 16 * 4);
  float* wl      = (float*)alloc(64 * 8 * 4);
  float* wr      = (float*)alloc(64 * 8 * 4);
  float* Wt2     = (float*)alloc(512 * 64 * 4);
  float* g       = (float*)alloc((size_t)N * 512 * 4);
  (void)ws_size;

  const int* srcp = edges;
  const int* dstp = edges + E;
  int SB = (N + 1 + NT - 1) / NT;   // must be <= 256

  detect_kernel<<<1, NT, 0, stream>>>((const int*)ei, flag, 2 * E);
  zero2_kernel<<<(N + NT - 1) / NT, NT, 0, stream>>>(deg, cursor, N);
  cvt_edges_kernel<<<(2 * E + NT - 1) / NT, NT, 0, stream>>>(ei, edges, flag, deg, E, 2 * E);

  // CSR build
  scan1_kernel<<<SB, NT, 0, stream>>>(deg, bsum, N);
  scan2_kernel<<<1, NT, 0, stream>>>(bsum, boff, SB);
  scan3_kernel<<<SB, NT, 0, stream>>>(deg, boff, rowptr, N);
  scatter_kernel<<<(E + NT - 1) / NT, NT, 0, stream>>>(srcp, dstp, rowptr, cursor, csr_src, E);

  // dense precomputation
  gemm1_kernel<<<(N + 31) / 32, NT, 0, stream>>>(x, W1, attl1, attr1, xl1, a1, N);
  foldw_kernel<<<1, 512, 0, stream>>>(W2, attl2, attr2, wl, wr);
  foldWt_kernel<<<(512 * 64 + NT - 1) / NT, NT, 0, stream>>>(W2, Wt2);

  // layer 1 aggregation (+ fused relu/bias + layer-2 attention dots)
  node_aggr1_kernel<<<(N + 3) / 4, NT, 0, stream>>>(rowptr, csr_src, a1, xl1, b1, wl, wr, hr, a2, N);

  // layer 2 aggregation -> g, then register-blocked GEMM epilogue
  node_aggr2_kernel<<<(N + 3) / 4, NT, 0, stream>>>(rowptr, csr_src, a2, hr, g, N);
  gemm3_kernel<<<(N + G3R - 1) / G3R, NT, 0, stream>>>(g, Wt2, b2, out, N);
}

// Round 7
// 365.083 us; speedup vs baseline: 1.2861x; 1.0005x over previous
//
#include <hip/hip_runtime.h>
#include <stdint.h>

#define NT 256

__device__ __forceinline__ float lrelu(float x) { return x > 0.f ? x : 0.2f * x; }

__device__ __forceinline__ float b2f(unsigned short u) {
  union { unsigned int i; float f; } v; v.i = ((unsigned int)u) << 16; return v.f;
}
__device__ __forceinline__ unsigned short f2b(float f) {
  unsigned int u = __float_as_uint(f);
  return (unsigned short)((u + 0x7fffu + ((u >> 16) & 1u)) >> 16);   // RNE
}

// ---- edge dtype detection (int32 vs int64) ----
__global__ void detect_kernel(const int* __restrict__ ei, int* __restrict__ flag, int twoE) {
  __shared__ int any;
  if (threadIdx.x == 0) any = 0;
  __syncthreads();
  int n = twoE < 4096 ? twoE : 4096;
  for (int i = threadIdx.x * 2 + 1; i < n; i += 2 * NT)
    if (ei[i] != 0) any = 1;   // benign race, same value
  __syncthreads();
  if (threadIdx.x == 0) *flag = any;   // 1 -> int32 data, 0 -> int64
}

// ---- convert edges + fused dst histogram ----
__global__ void cvt_edges_kernel(const void* __restrict__ ei, int* __restrict__ out,
                                 const int* __restrict__ flag, int* __restrict__ deg,
                                 int E, int twoE) {
  int i = blockIdx.x * NT + threadIdx.x;
  if (i >= twoE) return;
  int v;
  if (*flag) v = ((const int*)ei)[i];
  else       v = (int)((const long long*)ei)[i];
  out[i] = v;
  if (i >= E) atomicAdd(&deg[v], 1);   // dst half
}

// ---- CSR build ----
__global__ void zero2_kernel(int* __restrict__ a, int* __restrict__ b, int n) {
  int i = blockIdx.x * NT + threadIdx.x;
  if (i < n) { a[i] = 0; b[i] = 0; }
}

__global__ void scan1_kernel(const int* __restrict__ deg, int* __restrict__ bsum, int N) {
  __shared__ int sm[NT];
  int idx = blockIdx.x * NT + threadIdx.x;
  sm[threadIdx.x] = (idx < N) ? deg[idx] : 0;
  __syncthreads();
  for (int s = NT / 2; s > 0; s >>= 1) {
    if (threadIdx.x < s) sm[threadIdx.x] += sm[threadIdx.x + s];
    __syncthreads();
  }
  if (threadIdx.x == 0) bsum[blockIdx.x] = sm[0];
}

__global__ void scan2_kernel(const int* __restrict__ bsum, int* __restrict__ boff, int SB) {
  __shared__ int sm[NT];
  int t = threadIdx.x;
  int v = (t < SB) ? bsum[t] : 0;
  sm[t] = v;
  __syncthreads();
  for (int s = 1; s < NT; s <<= 1) {
    int add = (t >= s) ? sm[t - s] : 0;
    __syncthreads();
    sm[t] += add;
    __syncthreads();
  }
  if (t < SB) boff[t] = sm[t] - v;   // exclusive
}

__global__ void scan3_kernel(const int* __restrict__ deg, const int* __restrict__ boff,
                             int* __restrict__ rowptr, int N) {
  __shared__ int sm[NT];
  int idx = blockIdx.x * NT + threadIdx.x;
  int v = (idx < N) ? deg[idx] : 0;
  sm[threadIdx.x] = v;
  __syncthreads();
  for (int s = 1; s < NT; s <<= 1) {
    int add = (threadIdx.x >= s) ? sm[threadIdx.x - s] : 0;
    __syncthreads();
    sm[threadIdx.x] += add;
    __syncthreads();
  }
  if (idx <= N) rowptr[idx] = boff[blockIdx.x] + sm[threadIdx.x] - v;  // exclusive scan
}

__global__ void scatter_kernel(const int* __restrict__ src, const int* __restrict__ dst,
                               const int* __restrict__ rowptr, int* __restrict__ cursor,
                               int* __restrict__ csr_src, int E) {
  int e = blockIdx.x * NT + threadIdx.x;
  if (e >= E) return;
  int d = dst[e];
  int pos = rowptr[d] + atomicAdd(&cursor[d], 1);
  csr_src[pos] = src[e];
}

// ---- layer 1 GEMM + attention dots: xl1(bf16) = x@W1, a1 = [a_l | a_r] ----
__global__ void __launch_bounds__(NT)
gemm1_kernel(const float* __restrict__ x, const float* __restrict__ W1,
             const float* __restrict__ attl, const float* __restrict__ attr,
             unsigned short* __restrict__ xl1b, float* __restrict__ a1, int N) {
  __shared__ float Ws[128 * 64];
  __shared__ float xs[32][128];
  for (int i = threadIdx.x; i < 128 * 16; i += NT)
    *(float4*)&Ws[i * 4] = *(const float4*)&W1[i * 4];
  int row0 = blockIdx.x * 32;
  for (int i = threadIdx.x; i < 32 * 32; i += NT) {
    int r = i >> 5, c4 = i & 31;
    int n = row0 + r;
    float4 v = make_float4(0.f, 0.f, 0.f, 0.f);
    if (n < N) v = *(const float4*)&x[(size_t)n * 128 + c4 * 4];
    *(float4*)&xs[r][c4 * 4] = v;
  }
  __syncthreads();
  int w = threadIdx.x >> 6;
  int lane = threadIdx.x & 63;
  float al = attl[lane], ar = attr[lane];
  for (int rr = 0; rr < 8; ++rr) {
    int n = row0 + w * 8 + rr;
    if (n >= N) break;
    float acc = 0.f;
#pragma unroll 8
    for (int k = 0; k < 128; ++k) acc += xs[w * 8 + rr][k] * Ws[k * 64 + lane];
    xl1b[(size_t)n * 64 + lane] = f2b(acc);
    float pl = acc * al;
    float pr = acc * ar;
#pragma unroll
    for (int m = 1; m < 8; m <<= 1) {
      pl += __shfl_xor(pl, m, 64);
      pr += __shfl_xor(pr, m, 64);
    }
    if ((lane & 7) == 0) {
      int h = lane >> 3;
      a1[n * 16 + h] = pl;
      a1[n * 16 + 8 + h] = pr;
    }
  }
}

// ---- fold W2 with att vectors ----
__global__ void foldw_kernel(const float* __restrict__ W2, const float* __restrict__ attl2,
                             const float* __restrict__ attr2, float* __restrict__ wl,
                             float* __restrict__ wr) {
  int t = threadIdx.x;           // 0..511
  int k = t >> 3, h = t & 7;
  float sl = 0.f, sr = 0.f;
  for (int f = 0; f < 64; ++f) {
    float w = W2[k * 512 + h * 64 + f];
    sl += w * attl2[h * 64 + f];
    sr += w * attr2[h * 64 + f];
  }
  wl[k * 8 + h] = sl;
  wr[k * 8 + h] = sr;
}

// ---- Wt2[hk][f] = W2[k, h*64+f] * 0.125 ----
__global__ void foldWt_kernel(const float* __restrict__ W2, float* __restrict__ Wt2) {
  int idx = blockIdx.x * NT + threadIdx.x;
  if (idx >= 512 * 64) return;
  int f = idx & 63;
  int hk = idx >> 6;
  int h = hk >> 6, k = hk & 63;
  Wt2[idx] = W2[k * 512 + h * 64 + f] * 0.125f;
}

// ---- layer1: single-pass softmax+aggregation, bf16 gathers ----
__global__ void __launch_bounds__(NT)
node_aggr1_kernel(const int* __restrict__ rowptr, const int* __restrict__ csr_src,
                  const float* __restrict__ a1, const unsigned short* __restrict__ xl1b,
                  const float* __restrict__ b1, const float* __restrict__ wl,
                  const float* __restrict__ wr, unsigned short* __restrict__ hrb,
                  float* __restrict__ a2, int N) {
  __shared__ float ps[4][64][8];
  __shared__ int ss[4][64];
  int w = threadIdx.x >> 6;
  int n = blockIdx.x * 4 + w;
  if (n >= N) return;
  int lane = threadIdx.x & 63;
  int hown = lane >> 3;
  int base = rowptr[n];
  int deg = rowptr[n + 1] - base;

  float4 r0 = *(const float4*)(a1 + n * 16 + 8);
  float4 r1 = *(const float4*)(a1 + n * 16 + 12);
  float ar[8] = {r0.x, r0.y, r0.z, r0.w, r1.x, r1.y, r1.z, r1.w};

  const unsigned short* xp = xl1b + lane;
  float acc = 0.f;
  float dnl[8] = {0.f, 0.f, 0.f, 0.f, 0.f, 0.f, 0.f, 0.f};

  for (int j0 = 0; j0 < deg; j0 += 64) {
    int cnt = deg - j0; if (cnt > 64) cnt = 64;
    if (lane < cnt) {
      int s = csr_src[base + j0 + lane];
      ss[w][lane] = s;
      float4 l0 = *(const float4*)(a1 + s * 16);
      float4 l1 = *(const float4*)(a1 + s * 16 + 4);
      float p0 = __expf(lrelu(l0.x + ar[0]));
      float p1 = __expf(lrelu(l0.y + ar[1]));
      float p2 = __expf(lrelu(l0.z + ar[2]));
      float p3 = __expf(lrelu(l0.w + ar[3]));
      float p4 = __expf(lrelu(l1.x + ar[4]));
      float p5 = __expf(lrelu(l1.y + ar[5]));
      float p6 = __expf(lrelu(l1.z + ar[6]));
      float p7 = __expf(lrelu(l1.w + ar[7]));
      dnl[0] += p0; dnl[1] += p1; dnl[2] += p2; dnl[3] += p3;
      dnl[4] += p4; dnl[5] += p5; dnl[6] += p6; dnl[7] += p7;
      *(float4*)&ps[w][lane][0] = make_float4(p0, p1, p2, p3);
      *(float4*)&ps[w][lane][4] = make_float4(p4, p5, p6, p7);
    }
    asm volatile("s_waitcnt lgkmcnt(0)" ::: "memory");
    int j = 0;
    for (; j + 8 <= cnt; j += 8) {
      int s0 = ss[w][j+0], s1 = ss[w][j+1], s2 = ss[w][j+2], s3 = ss[w][j+3];
      int s4 = ss[w][j+4], s5 = ss[w][j+5], s6 = ss[w][j+6], s7 = ss[w][j+7];
      float q0 = ps[w][j+0][hown], q1 = ps[w][j+1][hown];
      float q2 = ps[w][j+2][hown], q3 = ps[w][j+3][hown];
      float q4 = ps[w][j+4][hown], q5 = ps[w][j+5][hown];
      float q6 = ps[w][j+6][hown], q7 = ps[w][j+7][hown];
      float v0 = b2f(xp[(size_t)s0 * 64]), v1 = b2f(xp[(size_t)s1 * 64]);
      float v2 = b2f(xp[(size_t)s2 * 64]), v3 = b2f(xp[(size_t)s3 * 64]);
      float v4 = b2f(xp[(size_t)s4 * 64]), v5 = b2f(xp[(size_t)s5 * 64]);
      float v6 = b2f(xp[(size_t)s6 * 64]), v7 = b2f(xp[(size_t)s7 * 64]);
      acc += q0*v0 + q1*v1 + q2*v2 + q3*v3 + q4*v4 + q5*v5 + q6*v6 + q7*v7;
    }
    for (; j < cnt; ++j) {
      int s = ss[w][j];
      acc += ps[w][j][hown] * b2f(xp[(size_t)s * 64]);
    }
  }
#pragma unroll
  for (int m = 1; m < 64; m <<= 1) {
#pragma unroll
    for (int h = 0; h < 8; ++h) dnl[h] += __shfl_xor(dnl[h], m, 64);
  }
  float dnh = dnl[0];
#pragma unroll
  for (int h = 1; h < 8; ++h) if (hown == h) dnh = dnl[h];

  acc = acc / (dnh + 1e-16f);
  float hv = fmaxf(acc + b1[lane], 0.f);   // relu(out1 + b1)
  hrb[(size_t)n * 64 + lane] = f2b(hv);

  // layer-2 attention dots
  float tl[8], tr[8];
#pragma unroll
  for (int h2 = 0; h2 < 8; ++h2) { tl[h2] = hv * wl[lane * 8 + h2]; tr[h2] = hv * wr[lane * 8 + h2]; }
#pragma unroll
  for (int m = 1; m < 64; m <<= 1) {
#pragma unroll
    for (int h2 = 0; h2 < 8; ++h2) { tl[h2] += __shfl_xor(tl[h2], m, 64); tr[h2] += __shfl_xor(tr[h2], m, 64); }
  }
  if (lane == 0) {
#pragma unroll
    for (int h2 = 0; h2 < 8; ++h2) {
      a2[n * 16 + h2] = tl[h2];
      a2[n * 16 + 8 + h2] = tr[h2];
    }
  }
}

// ---- layer2: single-pass softmax+aggregation -> normalized g (bf16) ----
__global__ void __launch_bounds__(NT)
node_aggr2_kernel(const int* __restrict__ rowptr, const int* __restrict__ csr_src,
                  const float* __restrict__ a2, const unsigned short* __restrict__ hrb,
                  unsigned short* __restrict__ gb, int N) {
  __shared__ float ps[4][64][8];
  __shared__ int ss[4][64];
  int w = threadIdx.x >> 6;
  int n = blockIdx.x * 4 + w;
  if (n >= N) return;
  int lane = threadIdx.x & 63;
  int base = rowptr[n];
  int deg = rowptr[n + 1] - base;

  float4 r0 = *(const float4*)(a2 + n * 16 + 8);
  float4 r1 = *(const float4*)(a2 + n * 16 + 12);
  float ar[8] = {r0.x, r0.y, r0.z, r0.w, r1.x, r1.y, r1.z, r1.w};

  const unsigned short* hp = hrb + lane;
  float acc[8] = {0.f, 0.f, 0.f, 0.f, 0.f, 0.f, 0.f, 0.f};
  float dnl[8] = {0.f, 0.f, 0.f, 0.f, 0.f, 0.f, 0.f, 0.f};

  for (int j0 = 0; j0 < deg; j0 += 64) {
    int cnt = deg - j0; if (cnt > 64) cnt = 64;
    if (lane < cnt) {
      int s = csr_src[base + j0 + lane];
      ss[w][lane] = s;
      float4 l0 = *(const float4*)(a2 + s * 16);
      float4 l1 = *(const float4*)(a2 + s * 16 + 4);
      float p0 = __expf(lrelu(l0.x + ar[0]));
      float p1 = __expf(lrelu(l0.y + ar[1]));
      float p2 = __expf(lrelu(l0.z + ar[2]));
      float p3 = __expf(lrelu(l0.w + ar[3]));
      float p4 = __expf(lrelu(l1.x + ar[4]));
      float p5 = __expf(lrelu(l1.y + ar[5]));
      float p6 = __expf(lrelu(l1.z + ar[6]));
      float p7 = __expf(lrelu(l1.w + ar[7]));
      dnl[0] += p0; dnl[1] += p1; dnl[2] += p2; dnl[3] += p3;
      dnl[4] += p4; dnl[5] += p5; dnl[6] += p6; dnl[7] += p7;
      *(float4*)&ps[w][lane][0] = make_float4(p0, p1, p2, p3);
      *(float4*)&ps[w][lane][4] = make_float4(p4, p5, p6, p7);
    }
    asm volatile("s_waitcnt lgkmcnt(0)" ::: "memory");
    int j = 0;
    for (; j + 4 <= cnt; j += 4) {
      int s0 = ss[w][j+0], s1 = ss[w][j+1], s2 = ss[w][j+2], s3 = ss[w][j+3];
      float v0 = b2f(hp[(size_t)s0 * 64]), v1 = b2f(hp[(size_t)s1 * 64]);
      float v2 = b2f(hp[(size_t)s2 * 64]), v3 = b2f(hp[(size_t)s3 * 64]);
      float4 pa0 = *(const float4*)&ps[w][j+0][0];
      float4 pb0 = *(const float4*)&ps[w][j+0][4];
      float4 pa1 = *(const float4*)&ps[w][j+1][0];
      float4 pb1 = *(const float4*)&ps[w][j+1][4];
      float4 pa2 = *(const float4*)&ps[w][j+2][0];
      float4 pb2 = *(const float4*)&ps[w][j+2][4];
      float4 pa3 = *(const float4*)&ps[w][j+3][0];
      float4 pb3 = *(const float4*)&ps[w][j+3][4];
      acc[0] += pa0.x*v0 + pa1.x*v1 + pa2.x*v2 + pa3.x*v3;
      acc[1] += pa0.y*v0 + pa1.y*v1 + pa2.y*v2 + pa3.y*v3;
      acc[2] += pa0.z*v0 + pa1.z*v1 + pa2.z*v2 + pa3.z*v3;
      acc[3] += pa0.w*v0 + pa1.w*v1 + pa2.w*v2 + pa3.w*v3;
      acc[4] += pb0.x*v0 + pb1.x*v1 + pb2.x*v2 + pb3.x*v3;
      acc[5] += pb0.y*v0 + pb1.y*v1 + pb2.y*v2 + pb3.y*v3;
      acc[6] += pb0.z*v0 + pb1.z*v1 + pb2.z*v2 + pb3.z*v3;
      acc[7] += pb0.w*v0 + pb1.w*v1 + pb2.w*v2 + pb3.w*v3;
    }
    for (; j < cnt; ++j) {
      int s = ss[w][j];
      float hv = b2f(hp[(size_t)s * 64]);
      float4 pa = *(const float4*)&ps[w][j][0];
      float4 pb = *(const float4*)&ps[w][j][4];
      acc[0] += pa.x * hv; acc[1] += pa.y * hv; acc[2] += pa.z * hv; acc[3] += pa.w * hv;
      acc[4] += pb.x * hv; acc[5] += pb.y * hv; acc[6] += pb.z * hv; acc[7] += pb.w * hv;
    }
  }
#pragma unroll
  for (int m = 1; m < 64; m <<= 1) {
#pragma unroll
    for (int h = 0; h < 8; ++h) dnl[h] += __shfl_xor(dnl[h], m, 64);
  }
#pragma unroll
  for (int h = 0; h < 8; ++h) {
    float v = acc[h] * (1.f / (dnl[h] + 1e-16f));
    gb[(size_t)n * 512 + h * 64 + lane] = f2b(v);
  }
}

// ---- register-blocked fp32 GEMM: out[N,64] = g(bf16)[N,512] @ Wt2[512,64] + b2 ----
#define G3R 128
__global__ void __launch_bounds__(NT)
gemm3_kernel(const unsigned short* __restrict__ gb, const float* __restrict__ Wt2,
             const float* __restrict__ b2, float* __restrict__ out, int N) {
  __shared__ float gsT[32][G3R + 4];   // [k][row], padded
  __shared__ float wsk[32][64];        // [k][f]
  int row0 = blockIdx.x * G3R;
  int tid = threadIdx.x;
  int cg = (tid & 7) * 8;      // col base (8 cols)
  int rg = (tid >> 3) * 4;     // row base within block (4 rows)
  float acc[4][8];
#pragma unroll
  for (int r = 0; r < 4; ++r)
#pragma unroll
    for (int c = 0; c < 8; ++c) acc[r][c] = 0.f;

  for (int k0 = 0; k0 < 512; k0 += 32) {
    __syncthreads();
    for (int i = tid; i < 512; i += NT)
      *(float4*)&wsk[i >> 4][(i & 15) * 4] =
          *(const float4*)&Wt2[(size_t)(k0 + (i >> 4)) * 64 + (i & 15) * 4];
    {
      int r = tid >> 1;
      int n = row0 + r;
      int ko = (tid & 1) * 16;
      if (n < N) {
        const uint4* gp = (const uint4*)&gb[(size_t)n * 512 + k0 + ko];
        uint4 q0 = gp[0], q1 = gp[1];   // 16 bf16
        unsigned int qq[8] = {q0.x, q0.y, q0.z, q0.w, q1.x, q1.y, q1.z, q1.w};
#pragma unroll
        for (int q = 0; q < 8; ++q) {
          gsT[ko + q * 2 + 0][r] = b2f((unsigned short)(qq[q] & 0xffffu));
          gsT[ko + q * 2 + 1][r] = b2f((unsigned short)(qq[q] >> 16));
        }
      } else {
#pragma unroll
        for (int q = 0; q < 16; ++q) gsT[ko + q][r] = 0.f;
      }
    }
    __syncthreads();
#pragma unroll
    for (int k = 0; k < 32; ++k) {
      float gv[4], wv[8];
      *(float4*)&gv[0] = *(const float4*)&gsT[k][rg];
      *(float4*)&wv[0] = *(const float4*)&wsk[k][cg];
      *(float4*)&wv[4] = *(const float4*)&wsk[k][cg + 4];
#pragma unroll
      for (int r = 0; r < 4; ++r)
#pragma unroll
        for (int c = 0; c < 8; ++c) acc[r][c] += gv[r] * wv[c];
    }
  }
  float bv[8];
#pragma unroll
  for (int c = 0; c < 8; ++c) bv[c] = b2[cg + c];
#pragma unroll
  for (int r = 0; r < 4; ++r) {
    int n = row0 + rg + r;
    if (n < N) {
      float4 o0 = make_float4(acc[r][0] + bv[0], acc[r][1] + bv[1],
                              acc[r][2] + bv[2], acc[r][3] + bv[3]);
      float4 o1 = make_float4(acc[r][4] + bv[4], acc[r][5] + bv[5],
                              acc[r][6] + bv[6], acc[r][7] + bv[7]);
      *(float4*)&out[(size_t)n * 64 + cg] = o0;
      *(float4*)&out[(size_t)n * 64 + cg + 4] = o1;
    }
  }
}

extern "C" void kernel_launch(void* const* d_in, const int* in_sizes, int n_in,
                              void* d_out, int out_size, void* d_ws, size_t ws_size,
                              hipStream_t stream) {
  const float* x     = (const float*)d_in[0];
  const void*  ei    = d_in[1];
  const float* W1    = (const float*)d_in[2];
  const float* attl1 = (const float*)d_in[3];
  const float* attr1 = (const float*)d_in[4];
  const float* b1    = (const float*)d_in[5];
  const float* W2    = (const float*)d_in[6];
  const float* attl2 = (const float*)d_in[7];
  const float* attr2 = (const float*)d_in[8];
  const float* b2    = (const float*)d_in[9];
  float* out = (float*)d_out;

  int N = in_sizes[0] / 128;
  int E = in_sizes[1] / 2;

  char* ws = (char*)d_ws;
  size_t off = 0;
  auto alloc = [&](size_t bytes) {
    char* p = ws + off;
    off += (bytes + 255) & ~size_t(255);
    return p;
  };
  int*            edges   = (int*)alloc((size_t)2 * E * 4);
  int*            flag    = (int*)alloc(256);
  int*            deg     = (int*)alloc((size_t)N * 4);
  int*            cursor  = (int*)alloc((size_t)N * 4);
  int*            rowptr  = (int*)alloc((size_t)(N + 1) * 4);
  int*            bsum    = (int*)alloc(1024);
  int*            boff    = (int*)alloc(1024);
  int*            csr_src = (int*)alloc((size_t)E * 4);
  unsigned short* xl1b    = (unsigned short*)alloc((size_t)N * 64 * 2);
  float*          a1      = (float*)alloc((size_t)N * 16 * 4);
  unsigned short* hrb     = (unsigned short*)alloc((size_t)N * 64 * 2);
  float*          a2      = (float*)alloc((size_t)N * 16 * 4);
  float*          wl      = (float*)alloc(64 * 8 * 4);
  float*          wr      = (float*)alloc(64 * 8 * 4);
  float*          Wt2     = (float*)alloc(512 * 64 * 4);
  unsigned short* gb      = (unsigned short*)alloc((size_t)N * 512 * 2);
  (void)ws_size;

  const int* srcp = edges;
  const int* dstp = edges + E;
  int SB = (N + 1 + NT - 1) / NT;   // must be <= 256

  detect_kernel<<<1, NT, 0, stream>>>((const int*)ei, flag, 2 * E);
  zero2_kernel<<<(N + NT - 1) / NT, NT, 0, stream>>>(deg, cursor, N);
  cvt_edges_kernel<<<(2 * E + NT - 1) / NT, NT, 0, stream>>>(ei, edges, flag, deg, E, 2 * E);

  // CSR build
  scan1_kernel<<<SB, NT, 0, stream>>>(deg, bsum, N);
  scan2_kernel<<<1, NT, 0, stream>>>(bsum, boff, SB);
  scan3_kernel<<<SB, NT, 0, stream>>>(deg, boff, rowptr, N);
  scatter_kernel<<<(E + NT - 1) / NT, NT, 0, stream>>>(srcp, dstp, rowptr, cursor, csr_src, E);

  // dense precomputation
  gemm1_kernel<<<(N + 31) / 32, NT, 0, stream>>>(x, W1, attl1, attr1, xl1b, a1, N);
  foldw_kernel<<<1, 512, 0, stream>>>(W2, attl2, attr2, wl, wr);
  foldWt_kernel<<<(512 * 64 + NT - 1) / NT, NT, 0, stream>>>(W2, Wt2);

  // layer 1 aggregation (+ fused relu/bias + layer-2 attention dots)
  node_aggr1_kernel<<<(N + 3) / 4, NT, 0, stream>>>(rowptr, csr_src, a1, xl1b, b1, wl, wr, hrb, a2, N);

  // layer 2 aggregation -> g (bf16), then register-blocked GEMM epilogue
  node_aggr2_kernel<<<(N + 3) / 4, NT, 0, stream>>>(rowptr, csr_src, a2, hrb, gb, N);
  gemm3_kernel<<<(N + G3R - 1) / G3R, NT, 0, stream>>>(gb, Wt2, b2, out, N);
}

// Round 8
// 306.061 us; speedup vs baseline: 1.5341x; 1.1928x over previous
//
#include <hip/hip_runtime.h>
#include <stdint.h>

#define NT 256

__device__ __forceinline__ float lrelu(float x) { return x > 0.f ? x : 0.2f * x; }

__device__ __forceinline__ float b2f(unsigned short u) {
  union { unsigned int i; float f; } v; v.i = ((unsigned int)u) << 16; return v.f;
}
__device__ __forceinline__ unsigned short f2b(float f) {
  unsigned int u = __float_as_uint(f);
  return (unsigned short)((u + 0x7fffu + ((u >> 16) & 1u)) >> 16);   // RNE
}

// ---- edge dtype detection (int32 vs int64) ----
__global__ void detect_kernel(const int* __restrict__ ei, int* __restrict__ flag, int twoE) {
  __shared__ int any;
  if (threadIdx.x == 0) any = 0;
  __syncthreads();
  int n = twoE < 4096 ? twoE : 4096;
  for (int i = threadIdx.x * 2 + 1; i < n; i += 2 * NT)
    if (ei[i] != 0) any = 1;   // benign race, same value
  __syncthreads();
  if (threadIdx.x == 0) *flag = any;   // 1 -> int32 data, 0 -> int64
}

// ---- convert edges + fused dst histogram ----
__global__ void cvt_edges_kernel(const void* __restrict__ ei, int* __restrict__ out,
                                 const int* __restrict__ flag, int* __restrict__ deg,
                                 int E, int twoE) {
  int i = blockIdx.x * NT + threadIdx.x;
  if (i >= twoE) return;
  int v;
  if (*flag) v = ((const int*)ei)[i];
  else       v = (int)((const long long*)ei)[i];
  out[i] = v;
  if (i >= E) atomicAdd(&deg[v], 1);   // dst half
}

// ---- CSR build ----
__global__ void zero2_kernel(int* __restrict__ a, int* __restrict__ b, int n) {
  int i = blockIdx.x * NT + threadIdx.x;
  if (i < n) { a[i] = 0; b[i] = 0; }
}

__global__ void scan1_kernel(const int* __restrict__ deg, int* __restrict__ bsum, int N) {
  __shared__ int sm[NT];
  int idx = blockIdx.x * NT + threadIdx.x;
  sm[threadIdx.x] = (idx < N) ? deg[idx] : 0;
  __syncthreads();
  for (int s = NT / 2; s > 0; s >>= 1) {
    if (threadIdx.x < s) sm[threadIdx.x] += sm[threadIdx.x + s];
    __syncthreads();
  }
  if (threadIdx.x == 0) bsum[blockIdx.x] = sm[0];
}

__global__ void scan2_kernel(const int* __restrict__ bsum, int* __restrict__ boff, int SB) {
  __shared__ int sm[NT];
  int t = threadIdx.x;
  int v = (t < SB) ? bsum[t] : 0;
  sm[t] = v;
  __syncthreads();
  for (int s = 1; s < NT; s <<= 1) {
    int add = (t >= s) ? sm[t - s] : 0;
    __syncthreads();
    sm[t] += add;
    __syncthreads();
  }
  if (t < SB) boff[t] = sm[t] - v;   // exclusive
}

__global__ void scan3_kernel(const int* __restrict__ deg, const int* __restrict__ boff,
                             int* __restrict__ rowptr, int N) {
  __shared__ int sm[NT];
  int idx = blockIdx.x * NT + threadIdx.x;
  int v = (idx < N) ? deg[idx] : 0;
  sm[threadIdx.x] = v;
  __syncthreads();
  for (int s = 1; s < NT; s <<= 1) {
    int add = (threadIdx.x >= s) ? sm[threadIdx.x - s] : 0;
    __syncthreads();
    sm[threadIdx.x] += add;
    __syncthreads();
  }
  if (idx <= N) rowptr[idx] = boff[blockIdx.x] + sm[threadIdx.x] - v;  // exclusive scan
}

__global__ void scatter_kernel(const int* __restrict__ src, const int* __restrict__ dst,
                               const int* __restrict__ rowptr, int* __restrict__ cursor,
                               int* __restrict__ csr_src, int E) {
  int e = blockIdx.x * NT + threadIdx.x;
  if (e >= E) return;
  int d = dst[e];
  int pos = rowptr[d] + atomicAdd(&cursor[d], 1);
  csr_src[pos] = src[e];
}

// ---- layer 1 GEMM + attention dots: xl1(bf16) = x@W1, a1 = [a_l | a_r] ----
__global__ void __launch_bounds__(NT)
gemm1_kernel(const float* __restrict__ x, const float* __restrict__ W1,
             const float* __restrict__ attl, const float* __restrict__ attr,
             unsigned short* __restrict__ xl1b, float* __restrict__ a1, int N) {
  __shared__ float Ws[128 * 64];
  __shared__ float xs[32][128];
  for (int i = threadIdx.x; i < 128 * 16; i += NT)
    *(float4*)&Ws[i * 4] = *(const float4*)&W1[i * 4];
  int row0 = blockIdx.x * 32;
  for (int i = threadIdx.x; i < 32 * 32; i += NT) {
    int r = i >> 5, c4 = i & 31;
    int n = row0 + r;
    float4 v = make_float4(0.f, 0.f, 0.f, 0.f);
    if (n < N) v = *(const float4*)&x[(size_t)n * 128 + c4 * 4];
    *(float4*)&xs[r][c4 * 4] = v;
  }
  __syncthreads();
  int w = threadIdx.x >> 6;
  int lane = threadIdx.x & 63;
  float al = attl[lane], ar = attr[lane];
  for (int rr = 0; rr < 8; ++rr) {
    int n = row0 + w * 8 + rr;
    if (n >= N) break;
    float acc = 0.f;
#pragma unroll 8
    for (int k = 0; k < 128; ++k) acc += xs[w * 8 + rr][k] * Ws[k * 64 + lane];
    xl1b[(size_t)n * 64 + lane] = f2b(acc);
    float pl = acc * al;
    float pr = acc * ar;
#pragma unroll
    for (int m = 1; m < 8; m <<= 1) {
      pl += __shfl_xor(pl, m, 64);
      pr += __shfl_xor(pr, m, 64);
    }
    if ((lane & 7) == 0) {
      int h = lane >> 3;
      a1[n * 16 + h] = pl;
      a1[n * 16 + 8 + h] = pr;
    }
  }
}

// ---- fold W2 with att vectors ----
__global__ void foldw_kernel(const float* __restrict__ W2, const float* __restrict__ attl2,
                             const float* __restrict__ attr2, float* __restrict__ wl,
                             float* __restrict__ wr) {
  int t = threadIdx.x;           // 0..511
  int k = t >> 3, h = t & 7;
  float sl = 0.f, sr = 0.f;
  for (int f = 0; f < 64; ++f) {
    float w = W2[k * 512 + h * 64 + f];
    sl += w * attl2[h * 64 + f];
    sr += w * attr2[h * 64 + f];
  }
  wl[k * 8 + h] = sl;
  wr[k * 8 + h] = sr;
}

// ---- Wt2[hk][f] = W2[k, h*64+f] * 0.125 ----
__global__ void foldWt_kernel(const float* __restrict__ W2, float* __restrict__ Wt2) {
  int idx = blockIdx.x * NT + threadIdx.x;
  if (idx >= 512 * 64) return;
  int f = idx & 63;
  int hk = idx >> 6;
  int h = hk >> 6, k = hk & 63;
  Wt2[idx] = W2[k * 512 + h * 64 + f] * 0.125f;
}

// ---- layer1: single-pass softmax+aggregation, all-lane staging, no butterflies ----
// stage layout: lane = j8*8 + hstage (8 edge slots x 8 heads)
// consume layout: lane = hown*8 + feat
__global__ void __launch_bounds__(NT)
node_aggr1_kernel(const int* __restrict__ rowptr, const int* __restrict__ csr_src,
                  const float* __restrict__ a1, const unsigned short* __restrict__ xl1b,
                  const float* __restrict__ b1, unsigned short* __restrict__ hrb, int N) {
  __shared__ float ps[4][64][8];
  __shared__ int ss[4][64];
  int w = threadIdx.x >> 6;
  int n = blockIdx.x * 4 + w;
  if (n >= N) return;
  int lane = threadIdx.x & 63;
  int hstage = lane & 7;
  int j8 = lane >> 3;
  int hown = lane >> 3;
  int base = rowptr[n];
  int deg = rowptr[n + 1] - base;

  float arh = a1[n * 16 + 8 + hstage];
  const unsigned short* xp = xl1b + lane;
  float acc = 0.f, dn = 0.f;

  for (int j0 = 0; j0 < deg; j0 += 64) {
    int cnt = deg - j0; if (cnt > 64) cnt = 64;
    if (lane < cnt) ss[w][lane] = csr_src[base + j0 + lane];
    asm volatile("s_waitcnt lgkmcnt(0)" ::: "memory");
    for (int jj = 0; jj < cnt; jj += 8) {
      int j = jj + j8;
      if (j < cnt) {
        int s = ss[w][j];
        float p = __expf(lrelu(a1[(unsigned)s * 16 + hstage] + arh));
        ps[w][j][hstage] = p;
      }
    }
    asm volatile("s_waitcnt lgkmcnt(0)" ::: "memory");
    int j = 0;
    for (; j + 4 <= cnt; j += 4) {
      int s0 = ss[w][j+0], s1 = ss[w][j+1], s2 = ss[w][j+2], s3 = ss[w][j+3];
      float p0 = ps[w][j+0][hown], p1 = ps[w][j+1][hown];
      float p2 = ps[w][j+2][hown], p3 = ps[w][j+3][hown];
      float v0 = b2f(xp[(unsigned)s0 * 64]), v1 = b2f(xp[(unsigned)s1 * 64]);
      float v2 = b2f(xp[(unsigned)s2 * 64]), v3 = b2f(xp[(unsigned)s3 * 64]);
      dn += (p0 + p1) + (p2 + p3);
      acc += p0 * v0 + p1 * v1 + p2 * v2 + p3 * v3;
    }
    for (; j < cnt; ++j) {
      int s = ss[w][j];
      float p = ps[w][j][hown];
      dn += p;
      acc += p * b2f(xp[(unsigned)s * 64]);
    }
  }
  acc = acc / (dn + 1e-16f);
  float hv = fmaxf(acc + b1[lane], 0.f);   // relu(out1 + b1)
  hrb[(size_t)n * 64 + lane] = f2b(hv);
}

// ---- layer-2 attention dots as a streaming kernel: a2[n,16] = hr[n,:] @ [wl|wr] ----
#define A2N 256
__global__ void __launch_bounds__(NT)
a2dots_kernel(const unsigned short* __restrict__ hrb, const float* __restrict__ wl,
              const float* __restrict__ wr, float* __restrict__ a2, int N) {
  __shared__ unsigned short hs[A2N][65];   // odd stride: conflict-light u16 reads
  __shared__ float wls[64 * 8], wrs[64 * 8];
  int tid = threadIdx.x;
  int n0 = blockIdx.x * A2N;
  for (int i = tid; i < 512; i += NT) { wls[i] = wl[i]; wrs[i] = wr[i]; }
  for (int i = tid; i < A2N * 8; i += NT) {     // uint4 chunks (8 bf16 each)
    int r = i >> 3, seg = i & 7;
    int n = n0 + r;
    uint4 v = make_uint4(0, 0, 0, 0);
    if (n < N) v = *(const uint4*)&hrb[(size_t)n * 64 + seg * 8];
    int c = seg * 8;
    hs[r][c + 0] = (unsigned short)(v.x);
    hs[r][c + 1] = (unsigned short)(v.x >> 16);
    hs[r][c + 2] = (unsigned short)(v.y);
    hs[r][c + 3] = (unsigned short)(v.y >> 16);
    hs[r][c + 4] = (unsigned short)(v.z);
    hs[r][c + 5] = (unsigned short)(v.z >> 16);
    hs[r][c + 6] = (unsigned short)(v.w);
    hs[r][c + 7] = (unsigned short)(v.w >> 16);
  }
  __syncthreads();
  float tl[8], tr[8];
#pragma unroll
  for (int h = 0; h < 8; ++h) { tl[h] = 0.f; tr[h] = 0.f; }
#pragma unroll 4
  for (int k = 0; k < 64; ++k) {
    float hv = b2f(hs[tid][k]);
    float4 l0 = *(const float4*)&wls[k * 8];
    float4 l1 = *(const float4*)&wls[k * 8 + 4];
    float4 r0 = *(const float4*)&wrs[k * 8];
    float4 r1 = *(const float4*)&wrs[k * 8 + 4];
    tl[0] += hv * l0.x; tl[1] += hv * l0.y; tl[2] += hv * l0.z; tl[3] += hv * l0.w;
    tl[4] += hv * l1.x; tl[5] += hv * l1.y; tl[6] += hv * l1.z; tl[7] += hv * l1.w;
    tr[0] += hv * r0.x; tr[1] += hv * r0.y; tr[2] += hv * r0.z; tr[3] += hv * r0.w;
    tr[4] += hv * r1.x; tr[5] += hv * r1.y; tr[6] += hv * r1.z; tr[7] += hv * r1.w;
  }
  int n = n0 + tid;
  if (n < N) {
    *(float4*)&a2[n * 16 + 0]  = make_float4(tl[0], tl[1], tl[2], tl[3]);
    *(float4*)&a2[n * 16 + 4]  = make_float4(tl[4], tl[5], tl[6], tl[7]);
    *(float4*)&a2[n * 16 + 8]  = make_float4(tr[0], tr[1], tr[2], tr[3]);
    *(float4*)&a2[n * 16 + 12] = make_float4(tr[4], tr[5], tr[6], tr[7]);
  }
}

// ---- layer2: single-pass softmax+aggregation -> normalized g (bf16) ----
__global__ void __launch_bounds__(NT)
node_aggr2_kernel(const int* __restrict__ rowptr, const int* __restrict__ csr_src,
                  const float* __restrict__ a2, const unsigned short* __restrict__ hrb,
                  unsigned short* __restrict__ gb, int N) {
  __shared__ float ps[4][64][8];
  __shared__ int ss[4][64];
  int w = threadIdx.x >> 6;
  int n = blockIdx.x * 4 + w;
  if (n >= N) return;
  int lane = threadIdx.x & 63;
  int hstage = lane & 7;
  int j8 = lane >> 3;
  int base = rowptr[n];
  int deg = rowptr[n + 1] - base;

  float arh = a2[n * 16 + 8 + hstage];
  const unsigned short* hp = hrb + lane;
  float acc[8] = {0.f, 0.f, 0.f, 0.f, 0.f, 0.f, 0.f, 0.f};
  float dn_own = 0.f;

  for (int j0 = 0; j0 < deg; j0 += 64) {
    int cnt = deg - j0; if (cnt > 64) cnt = 64;
    if (lane < cnt) ss[w][lane] = csr_src[base + j0 + lane];
    asm volatile("s_waitcnt lgkmcnt(0)" ::: "memory");
    for (int jj = 0; jj < cnt; jj += 8) {
      int j = jj + j8;
      if (j < cnt) {
        int s = ss[w][j];
        float p = __expf(lrelu(a2[(unsigned)s * 16 + hstage] + arh));
        ps[w][j][hstage] = p;
      }
    }
    asm volatile("s_waitcnt lgkmcnt(0)" ::: "memory");
    for (int j = 0; j < cnt; ++j) {
      int s = ss[w][j];
      float hv = b2f(hp[(unsigned)s * 64]);
      float4 pa = *(const float4*)&ps[w][j][0];
      float4 pb = *(const float4*)&ps[w][j][4];
      dn_own += ps[w][j][hstage];
      acc[0] += pa.x * hv; acc[1] += pa.y * hv; acc[2] += pa.z * hv; acc[3] += pa.w * hv;
      acc[4] += pb.x * hv; acc[5] += pb.y * hv; acc[6] += pb.z * hv; acc[7] += pb.w * hv;
    }
  }
#pragma unroll
  for (int h = 0; h < 8; ++h) {
    float dnh = __shfl(dn_own, h, 64);
    float v = acc[h] * (1.f / (dnh + 1e-16f));
    gb[(size_t)n * 512 + h * 64 + lane] = f2b(v);
  }
}

// ---- register-blocked fp32 GEMM: out[N,64] = g(bf16)[N,512] @ Wt2[512,64] + b2 ----
#define G3R 128
__global__ void __launch_bounds__(NT)
gemm3_kernel(const unsigned short* __restrict__ gb, const float* __restrict__ Wt2,
             const float* __restrict__ b2, float* __restrict__ out, int N) {
  __shared__ float gsT[32][G3R + 4];   // [k][row], padded
  __shared__ float wsk[32][64];        // [k][f]
  int row0 = blockIdx.x * G3R;
  int tid = threadIdx.x;
  int cg = (tid & 7) * 8;      // col base (8 cols)
  int rg = (tid >> 3) * 4;     // row base within block (4 rows)
  float acc[4][8];
#pragma unroll
  for (int r = 0; r < 4; ++r)
#pragma unroll
    for (int c = 0; c < 8; ++c) acc[r][c] = 0.f;

  for (int k0 = 0; k0 < 512; k0 += 32) {
    __syncthreads();
    for (int i = tid; i < 512; i += NT)
      *(float4*)&wsk[i >> 4][(i & 15) * 4] =
          *(const float4*)&Wt2[(size_t)(k0 + (i >> 4)) * 64 + (i & 15) * 4];
    {
      int r = tid >> 1;
      int n = row0 + r;
      int ko = (tid & 1) * 16;
      if (n < N) {
        const uint4* gp = (const uint4*)&gb[(size_t)n * 512 + k0 + ko];
        uint4 q0 = gp[0], q1 = gp[1];   // 16 bf16
        unsigned int qq[8] = {q0.x, q0.y, q0.z, q0.w, q1.x, q1.y, q1.z, q1.w};
#pragma unroll
        for (int q = 0; q < 8; ++q) {
          gsT[ko + q * 2 + 0][r] = b2f((unsigned short)(qq[q] & 0xffffu));
          gsT[ko + q * 2 + 1][r] = b2f((unsigned short)(qq[q] >> 16));
        }
      } else {
#pragma unroll
        for (int q = 0; q < 16; ++q) gsT[ko + q][r] = 0.f;
      }
    }
    __syncthreads();
#pragma unroll
    for (int k = 0; k < 32; ++k) {
      float gv[4], wv[8];
      *(float4*)&gv[0] = *(const float4*)&gsT[k][rg];
      *(float4*)&wv[0] = *(const float4*)&wsk[k][cg];
      *(float4*)&wv[4] = *(const float4*)&wsk[k][cg + 4];
#pragma unroll
      for (int r = 0; r < 4; ++r)
#pragma unroll
        for (int c = 0; c < 8; ++c) acc[r][c] += gv[r] * wv[c];
    }
  }
  float bv[8];
#pragma unroll
  for (int c = 0; c < 8; ++c) bv[c] = b2[cg + c];
#pragma unroll
  for (int r = 0; r < 4; ++r) {
    int n = row0 + rg + r;
    if (n < N) {
      float4 o0 = make_float4(acc[r][0] + bv[0], acc[r][1] + bv[1],
                              acc[r][2] + bv[2], acc[r][3] + bv[3]);
      float4 o1 = make_float4(acc[r][4] + bv[4], acc[r][5] + bv[5],
                              acc[r][6] + bv[6], acc[r][7] + bv[7]);
      *(float4*)&out[(size_t)n * 64 + cg] = o0;
      *(float4*)&out[(size_t)n * 64 + cg + 4] = o1;
    }
  }
}

extern "C" void kernel_launch(void* const* d_in, const int* in_sizes, int n_in,
                              void* d_out, int out_size, void* d_ws, size_t ws_size,
                              hipStream_t stream) {
  const float* x     = (const float*)d_in[0];
  const void*  ei    = d_in[1];
  const float* W1    = (const float*)d_in[2];
  const float* attl1 = (const float*)d_in[3];
  const float* attr1 = (const float*)d_in[4];
  const float* b1    = (const float*)d_in[5];
  const float* W2    = (const float*)d_in[6];
  const float* attl2 = (const float*)d_in[7];
  const float* attr2 = (const float*)d_in[8];
  const float* b2    = (const float*)d_in[9];
  float* out = (float*)d_out;

  int N = in_sizes[0] / 128;
  int E = in_sizes[1] / 2;

  char* ws = (char*)d_ws;
  size_t off = 0;
  auto alloc = [&](size_t bytes) {
    char* p = ws + off;
    off += (bytes + 255) & ~size_t(255);
    return p;
  };
  int*            edges   = (int*)alloc((size_t)2 * E * 4);
  int*            flag    = (int*)alloc(256);
  int*            deg     = (int*)alloc((size_t)N * 4);
  int*            cursor  = (int*)alloc((size_t)N * 4);
  int*            rowptr  = (int*)alloc((size_t)(N + 1) * 4);
  int*            bsum    = (int*)alloc(1024);
  int*            boff    = (int*)alloc(1024);
  int*            csr_src = (int*)alloc((size_t)E * 4);
  unsigned short* xl1b    = (unsigned short*)alloc((size_t)N * 64 * 2);
  float*          a1      = (float*)alloc((size_t)N * 16 * 4);
  unsigned short* hrb     = (unsigned short*)alloc((size_t)N * 64 * 2);
  float*          a2      = (float*)alloc((size_t)N * 16 * 4);
  float*          wl      = (float*)alloc(64 * 8 * 4);
  float*          wr      = (float*)alloc(64 * 8 * 4);
  float*          Wt2     = (float*)alloc(512 * 64 * 4);
  unsigned short* gb      = (unsigned short*)alloc((size_t)N * 512 * 2);
  (void)ws_size;

  const int* srcp = edges;
  const int* dstp = edges + E;
  int SB = (N + 1 + NT - 1) / NT;   // must be <= 256

  detect_kernel<<<1, NT, 0, stream>>>((const int*)ei, flag, 2 * E);
  zero2_kernel<<<(N + NT - 1) / NT, NT, 0, stream>>>(deg, cursor, N);
  cvt_edges_kernel<<<(2 * E + NT - 1) / NT, NT, 0, stream>>>(ei, edges, flag, deg, E, 2 * E);

  // CSR build
  scan1_kernel<<<SB, NT, 0, stream>>>(deg, bsum, N);
  scan2_kernel<<<1, NT, 0, stream>>>(bsum, boff, SB);
  scan3_kernel<<<SB, NT, 0, stream>>>(deg, boff, rowptr, N);
  scatter_kernel<<<(E + NT - 1) / NT, NT, 0, stream>>>(srcp, dstp, rowptr, cursor, csr_src, E);

  // dense precomputation
  gemm1_kernel<<<(N + 31) / 32, NT, 0, stream>>>(x, W1, attl1, attr1, xl1b, a1, N);
  foldw_kernel<<<1, 512, 0, stream>>>(W2, attl2, attr2, wl, wr);
  foldWt_kernel<<<(512 * 64 + NT - 1) / NT, NT, 0, stream>>>(W2, Wt2);

  // layer 1 aggregation (+ fused relu/bias)
  node_aggr1_kernel<<<(N + 3) / 4, NT, 0, stream>>>(rowptr, csr_src, a1, xl1b, b1, hrb, N);

  // layer-2 attention dots (streaming)
  a2dots_kernel<<<(N + A2N - 1) / A2N, NT, 0, stream>>>(hrb, wl, wr, a2, N);

  // layer 2 aggregation -> g (bf16), then register-blocked GEMM epilogue
  node_aggr2_kernel<<<(N + 3) / 4, NT, 0, stream>>>(rowptr, csr_src, a2, hrb, gb, N);
  gemm3_kernel<<<(N + G3R - 1) / G3R, NT, 0, stream>>>(gb, Wt2, b2, out, N);
}

// Round 9
// 269.428 us; speedup vs baseline: 1.7426x; 1.1360x over previous
//
#include <hip/hip_runtime.h>
#include <stdint.h>

#define NT 256

typedef __attribute__((ext_vector_type(8))) short bf16x8;
typedef __attribute__((ext_vector_type(4))) float f32x4;

__device__ __forceinline__ float lrelu(float x) { return x > 0.f ? x : 0.2f * x; }

__device__ __forceinline__ float b2f(unsigned short u) {
  union { unsigned int i; float f; } v; v.i = ((unsigned int)u) << 16; return v.f;
}
__device__ __forceinline__ unsigned short f2b(float f) {
  unsigned int u = __float_as_uint(f);
  return (unsigned short)((u + 0x7fffu + ((u >> 16) & 1u)) >> 16);   // RNE
}

// ---- edge dtype detection (int32 vs int64) ----
__global__ void detect_kernel(const int* __restrict__ ei, int* __restrict__ flag, int twoE) {
  __shared__ int any;
  if (threadIdx.x == 0) any = 0;
  __syncthreads();
  int n = twoE < 4096 ? twoE : 4096;
  for (int i = threadIdx.x * 2 + 1; i < n; i += 2 * NT)
    if (ei[i] != 0) any = 1;   // benign race, same value
  __syncthreads();
  if (threadIdx.x == 0) *flag = any;   // 1 -> int32 data, 0 -> int64
}

// ---- convert edges + fused dst histogram ----
__global__ void cvt_edges_kernel(const void* __restrict__ ei, int* __restrict__ out,
                                 const int* __restrict__ flag, int* __restrict__ deg,
                                 int E, int twoE) {
  int i = blockIdx.x * NT + threadIdx.x;
  if (i >= twoE) return;
  int v;
  if (*flag) v = ((const int*)ei)[i];
  else       v = (int)((const long long*)ei)[i];
  out[i] = v;
  if (i >= E) atomicAdd(&deg[v], 1);   // dst half
}

// ---- CSR build ----
__global__ void zero2_kernel(int* __restrict__ a, int* __restrict__ b, int n) {
  int i = blockIdx.x * NT + threadIdx.x;
  if (i < n) { a[i] = 0; b[i] = 0; }
}

__global__ void scan1_kernel(const int* __restrict__ deg, int* __restrict__ bsum, int N) {
  __shared__ int sm[NT];
  int idx = blockIdx.x * NT + threadIdx.x;
  sm[threadIdx.x] = (idx < N) ? deg[idx] : 0;
  __syncthreads();
  for (int s = NT / 2; s > 0; s >>= 1) {
    if (threadIdx.x < s) sm[threadIdx.x] += sm[threadIdx.x + s];
    __syncthreads();
  }
  if (threadIdx.x == 0) bsum[blockIdx.x] = sm[0];
}

__global__ void scan2_kernel(const int* __restrict__ bsum, int* __restrict__ boff, int SB) {
  __shared__ int sm[NT];
  int t = threadIdx.x;
  int v = (t < SB) ? bsum[t] : 0;
  sm[t] = v;
  __syncthreads();
  for (int s = 1; s < NT; s <<= 1) {
    int add = (t >= s) ? sm[t - s] : 0;
    __syncthreads();
    sm[t] += add;
    __syncthreads();
  }
  if (t < SB) boff[t] = sm[t] - v;   // exclusive
}

__global__ void scan3_kernel(const int* __restrict__ deg, const int* __restrict__ boff,
                             int* __restrict__ rowptr, int N) {
  __shared__ int sm[NT];
  int idx = blockIdx.x * NT + threadIdx.x;
  int v = (idx < N) ? deg[idx] : 0;
  sm[threadIdx.x] = v;
  __syncthreads();
  for (int s = 1; s < NT; s <<= 1) {
    int add = (threadIdx.x >= s) ? sm[threadIdx.x - s] : 0;
    __syncthreads();
    sm[threadIdx.x] += add;
    __syncthreads();
  }
  if (idx <= N) rowptr[idx] = boff[blockIdx.x] + sm[threadIdx.x] - v;  // exclusive scan
}

__global__ void scatter_kernel(const int* __restrict__ src, const int* __restrict__ dst,
                               const int* __restrict__ rowptr, int* __restrict__ cursor,
                               int* __restrict__ csr_src, int E) {
  int e = blockIdx.x * NT + threadIdx.x;
  if (e >= E) return;
  int d = dst[e];
  int pos = rowptr[d] + atomicAdd(&cursor[d], 1);
  csr_src[pos] = src[e];
}

// ---- layer 1 GEMM + attention dots: xl1(bf16) = x@W1, a1 = [a_l | a_r] ----
__global__ void __launch_bounds__(NT)
gemm1_kernel(const float* __restrict__ x, const float* __restrict__ W1,
             const float* __restrict__ attl, const float* __restrict__ attr,
             unsigned short* __restrict__ xl1b, float* __restrict__ a1, int N) {
  __shared__ float Ws[128 * 64];
  __shared__ float xs[32][128];
  for (int i = threadIdx.x; i < 128 * 16; i += NT)
    *(float4*)&Ws[i * 4] = *(const float4*)&W1[i * 4];
  int row0 = blockIdx.x * 32;
  for (int i = threadIdx.x; i < 32 * 32; i += NT) {
    int r = i >> 5, c4 = i & 31;
    int n = row0 + r;
    float4 v = make_float4(0.f, 0.f, 0.f, 0.f);
    if (n < N) v = *(const float4*)&x[(size_t)n * 128 + c4 * 4];
    *(float4*)&xs[r][c4 * 4] = v;
  }
  __syncthreads();
  int w = threadIdx.x >> 6;
  int lane = threadIdx.x & 63;
  float al = attl[lane], ar = attr[lane];
  for (int rr = 0; rr < 8; ++rr) {
    int n = row0 + w * 8 + rr;
    if (n >= N) break;
    float acc = 0.f;
#pragma unroll 8
    for (int k = 0; k < 128; ++k) acc += xs[w * 8 + rr][k] * Ws[k * 64 + lane];
    xl1b[(size_t)n * 64 + lane] = f2b(acc);
    float pl = acc * al;
    float pr = acc * ar;
#pragma unroll
    for (int m = 1; m < 8; m <<= 1) {
      pl += __shfl_xor(pl, m, 64);
      pr += __shfl_xor(pr, m, 64);
    }
    if ((lane & 7) == 0) {
      int h = lane >> 3;
      a1[n * 16 + h] = pl;
      a1[n * 16 + 8 + h] = pr;
    }
  }
}

// ---- fold W2 with att vectors ----
__global__ void foldw_kernel(const float* __restrict__ W2, const float* __restrict__ attl2,
                             const float* __restrict__ attr2, float* __restrict__ wl,
                             float* __restrict__ wr) {
  int t = threadIdx.x;           // 0..511
  int k = t >> 3, h = t & 7;
  float sl = 0.f, sr = 0.f;
  for (int f = 0; f < 64; ++f) {
    float w = W2[k * 512 + h * 64 + f];
    sl += w * attl2[h * 64 + f];
    sr += w * attr2[h * 64 + f];
  }
  wl[k * 8 + h] = sl;
  wr[k * 8 + h] = sr;
}

// ---- pack B fragments for MFMA epilogue:
// Bpack[((chunk*4+ct)*64 + lane)*8 + j] = bf16( W2[kk*512 + h*64 + f] * 0.125 )
//   where hk = chunk*32 + (lane>>4)*8 + j,  h = hk>>6, kk = hk&63,  f = ct*16 + (lane&15)
__global__ void foldB_kernel(const float* __restrict__ W2, unsigned short* __restrict__ Bpack) {
  int idx = blockIdx.x * NT + threadIdx.x;   // over 512*64
  if (idx >= 512 * 64) return;
  int j = idx & 7;
  int lane = (idx >> 3) & 63;
  int ctchunk = idx >> 9;
  int ct = ctchunk & 3;
  int chunk = ctchunk >> 2;
  int hk = chunk * 32 + ((lane >> 4) << 3) + j;
  int h = hk >> 6, kk = hk & 63;
  int f = ct * 16 + (lane & 15);
  Bpack[idx] = f2b(W2[kk * 512 + h * 64 + f] * 0.125f);
}

// ---- layer1: single-pass softmax+aggregation, all-lane staging, no butterflies ----
__global__ void __launch_bounds__(NT)
node_aggr1_kernel(const int* __restrict__ rowptr, const int* __restrict__ csr_src,
                  const float* __restrict__ a1, const unsigned short* __restrict__ xl1b,
                  const float* __restrict__ b1, unsigned short* __restrict__ hrb, int N) {
  __shared__ float ps[4][64][8];
  __shared__ int ss[4][64];
  int w = threadIdx.x >> 6;
  int n = blockIdx.x * 4 + w;
  if (n >= N) return;
  int lane = threadIdx.x & 63;
  int hstage = lane & 7;
  int j8 = lane >> 3;
  int hown = lane >> 3;
  int base = rowptr[n];
  int deg = rowptr[n + 1] - base;

  float arh = a1[n * 16 + 8 + hstage];
  const unsigned short* xp = xl1b + lane;
  float acc = 0.f, dn = 0.f;

  for (int j0 = 0; j0 < deg; j0 += 64) {
    int cnt = deg - j0; if (cnt > 64) cnt = 64;
    if (lane < cnt) ss[w][lane] = csr_src[base + j0 + lane];
    asm volatile("s_waitcnt lgkmcnt(0)" ::: "memory");
    for (int jj = 0; jj < cnt; jj += 8) {
      int j = jj + j8;
      if (j < cnt) {
        int s = ss[w][j];
        float p = __expf(lrelu(a1[(unsigned)s * 16 + hstage] + arh));
        ps[w][j][hstage] = p;
      }
    }
    asm volatile("s_waitcnt lgkmcnt(0)" ::: "memory");
    int j = 0;
    for (; j + 4 <= cnt; j += 4) {
      int s0 = ss[w][j+0], s1 = ss[w][j+1], s2 = ss[w][j+2], s3 = ss[w][j+3];
      float p0 = ps[w][j+0][hown], p1 = ps[w][j+1][hown];
      float p2 = ps[w][j+2][hown], p3 = ps[w][j+3][hown];
      float v0 = b2f(xp[(unsigned)s0 * 64]), v1 = b2f(xp[(unsigned)s1 * 64]);
      float v2 = b2f(xp[(unsigned)s2 * 64]), v3 = b2f(xp[(unsigned)s3 * 64]);
      dn += (p0 + p1) + (p2 + p3);
      acc += p0 * v0 + p1 * v1 + p2 * v2 + p3 * v3;
    }
    for (; j < cnt; ++j) {
      int s = ss[w][j];
      float p = ps[w][j][hown];
      dn += p;
      acc += p * b2f(xp[(unsigned)s * 64]);
    }
  }
  acc = acc / (dn + 1e-16f);
  float hv = fmaxf(acc + b1[lane], 0.f);   // relu(out1 + b1)
  hrb[(size_t)n * 64 + lane] = f2b(hv);
}

// ---- layer-2 attention dots as a streaming kernel ----
#define A2N 256
__global__ void __launch_bounds__(NT)
a2dots_kernel(const unsigned short* __restrict__ hrb, const float* __restrict__ wl,
              const float* __restrict__ wr, float* __restrict__ a2, int N) {
  __shared__ unsigned short hs[A2N][65];
  __shared__ float wls[64 * 8], wrs[64 * 8];
  int tid = threadIdx.x;
  int n0 = blockIdx.x * A2N;
  for (int i = tid; i < 512; i += NT) { wls[i] = wl[i]; wrs[i] = wr[i]; }
  for (int i = tid; i < A2N * 8; i += NT) {
    int r = i >> 3, seg = i & 7;
    int n = n0 + r;
    uint4 v = make_uint4(0, 0, 0, 0);
    if (n < N) v = *(const uint4*)&hrb[(size_t)n * 64 + seg * 8];
    int c = seg * 8;
    hs[r][c + 0] = (unsigned short)(v.x);
    hs[r][c + 1] = (unsigned short)(v.x >> 16);
    hs[r][c + 2] = (unsigned short)(v.y);
    hs[r][c + 3] = (unsigned short)(v.y >> 16);
    hs[r][c + 4] = (unsigned short)(v.z);
    hs[r][c + 5] = (unsigned short)(v.z >> 16);
    hs[r][c + 6] = (unsigned short)(v.w);
    hs[r][c + 7] = (unsigned short)(v.w >> 16);
  }
  __syncthreads();
  float tl[8], tr[8];
#pragma unroll
  for (int h = 0; h < 8; ++h) { tl[h] = 0.f; tr[h] = 0.f; }
#pragma unroll 4
  for (int k = 0; k < 64; ++k) {
    float hv = b2f(hs[tid][k]);
    float4 l0 = *(const float4*)&wls[k * 8];
    float4 l1 = *(const float4*)&wls[k * 8 + 4];
    float4 r0 = *(const float4*)&wrs[k * 8];
    float4 r1 = *(const float4*)&wrs[k * 8 + 4];
    tl[0] += hv * l0.x; tl[1] += hv * l0.y; tl[2] += hv * l0.z; tl[3] += hv * l0.w;
    tl[4] += hv * l1.x; tl[5] += hv * l1.y; tl[6] += hv * l1.z; tl[7] += hv * l1.w;
    tr[0] += hv * r0.x; tr[1] += hv * r0.y; tr[2] += hv * r0.z; tr[3] += hv * r0.w;
    tr[4] += hv * r1.x; tr[5] += hv * r1.y; tr[6] += hv * r1.z; tr[7] += hv * r1.w;
  }
  int n = n0 + tid;
  if (n < N) {
    *(float4*)&a2[n * 16 + 0]  = make_float4(tl[0], tl[1], tl[2], tl[3]);
    *(float4*)&a2[n * 16 + 4]  = make_float4(tl[4], tl[5], tl[6], tl[7]);
    *(float4*)&a2[n * 16 + 8]  = make_float4(tr[0], tr[1], tr[2], tr[3]);
    *(float4*)&a2[n * 16 + 12] = make_float4(tr[4], tr[5], tr[6], tr[7]);
  }
}

// ---- layer2: single-pass softmax+aggregation -> normalized g (bf16) ----
__global__ void __launch_bounds__(NT)
node_aggr2_kernel(const int* __restrict__ rowptr, const int* __restrict__ csr_src,
                  const float* __restrict__ a2, const unsigned short* __restrict__ hrb,
                  unsigned short* __restrict__ gb, int N) {
  __shared__ float ps[4][64][8];
  __shared__ int ss[4][64];
  int w = threadIdx.x >> 6;
  int n = blockIdx.x * 4 + w;
  if (n >= N) return;
  int lane = threadIdx.x & 63;
  int hstage = lane & 7;
  int j8 = lane >> 3;
  int base = rowptr[n];
  int deg = rowptr[n + 1] - base;

  float arh = a2[n * 16 + 8 + hstage];
  const unsigned short* hp = hrb + lane;
  float acc[8] = {0.f, 0.f, 0.f, 0.f, 0.f, 0.f, 0.f, 0.f};
  float dn_own = 0.f;

  for (int j0 = 0; j0 < deg; j0 += 64) {
    int cnt = deg - j0; if (cnt > 64) cnt = 64;
    if (lane < cnt) ss[w][lane] = csr_src[base + j0 + lane];
    asm volatile("s_waitcnt lgkmcnt(0)" ::: "memory");
    for (int jj = 0; jj < cnt; jj += 8) {
      int j = jj + j8;
      if (j < cnt) {
        int s = ss[w][j];
        float p = __expf(lrelu(a2[(unsigned)s * 16 + hstage] + arh));
        ps[w][j][hstage] = p;
      }
    }
    asm volatile("s_waitcnt lgkmcnt(0)" ::: "memory");
    for (int j = 0; j < cnt; ++j) {
      int s = ss[w][j];
      float hv = b2f(hp[(unsigned)s * 64]);
      float4 pa = *(const float4*)&ps[w][j][0];
      float4 pb = *(const float4*)&ps[w][j][4];
      dn_own += ps[w][j][hstage];
      acc[0] += pa.x * hv; acc[1] += pa.y * hv; acc[2] += pa.z * hv; acc[3] += pa.w * hv;
      acc[4] += pb.x * hv; acc[5] += pb.y * hv; acc[6] += pb.z * hv; acc[7] += pb.w * hv;
    }
  }
#pragma unroll
  for (int h = 0; h < 8; ++h) {
    float dnh = __shfl(dn_own, h, 64);
    float v = acc[h] * (1.f / (dnh + 1e-16f));
    gb[(size_t)n * 512 + h * 64 + lane] = f2b(v);
  }
}

// ---- MFMA epilogue GEMM: out[N,64] = gb[N,512](bf16) @ Bpack + b2 ----
// block = 256 threads = 4 waves; wave w handles rows [row0 + w*16, +16)
// A-frag: lane l holds gb[row0w + (l&15)][k0 + (l>>4)*8 + j]  (16B contiguous load)
// B-frag: pre-packed lane-ordered (foldB_kernel)
// C/D: col = lane&15 (+ct*16), row = row0w + (lane>>4)*4 + reg
__global__ void __launch_bounds__(NT)
gemm3_mfma_kernel(const unsigned short* __restrict__ gb,
                  const unsigned short* __restrict__ Bpack,
                  const float* __restrict__ b2, float* __restrict__ out, int N) {
  int w = threadIdx.x >> 6;
  int lane = threadIdx.x & 63;
  int row0w = blockIdx.x * 64 + w * 16;
  int arow = row0w + (lane & 15);
  if (arow >= N) arow = N - 1;          // clamp (stores are guarded)
  const unsigned short* ap = gb + (size_t)arow * 512 + ((lane >> 4) << 3);

  f32x4 acc[4];
#pragma unroll
  for (int ct = 0; ct < 4; ++ct) {
    float bb = b2[ct * 16 + (lane & 15)];
    acc[ct][0] = bb; acc[ct][1] = bb; acc[ct][2] = bb; acc[ct][3] = bb;
  }

#pragma unroll 4
  for (int chunk = 0; chunk < 16; ++chunk) {
    bf16x8 a = *(const bf16x8*)(ap + chunk * 32);
    const unsigned short* bp = Bpack + ((size_t)chunk * 4 * 64 + lane) * 8;
#pragma unroll
    for (int ct = 0; ct < 4; ++ct) {
      bf16x8 b = *(const bf16x8*)(bp + (size_t)ct * 64 * 8);
      acc[ct] = __builtin_amdgcn_mfma_f32_16x16x32_bf16(a, b, acc[ct], 0, 0, 0);
    }
  }

  int orow0 = row0w + ((lane >> 4) << 2);
#pragma unroll
  for (int ct = 0; ct < 4; ++ct) {
    int col = ct * 16 + (lane & 15);
#pragma unroll
    for (int r = 0; r < 4; ++r) {
      int n = orow0 + r;
      if (n < N) out[(size_t)n * 64 + col] = acc[ct][r];
    }
  }
}

extern "C" void kernel_launch(void* const* d_in, const int* in_sizes, int n_in,
                              void* d_out, int out_size, void* d_ws, size_t ws_size,
                              hipStream_t stream) {
  const float* x     = (const float*)d_in[0];
  const void*  ei    = d_in[1];
  const float* W1    = (const float*)d_in[2];
  const float* attl1 = (const float*)d_in[3];
  const float* attr1 = (const float*)d_in[4];
  const float* b1    = (const float*)d_in[5];
  const float* W2    = (const float*)d_in[6];
  const float* attl2 = (const float*)d_in[7];
  const float* attr2 = (const float*)d_in[8];
  const float* b2    = (const float*)d_in[9];
  float* out = (float*)d_out;

  int N = in_sizes[0] / 128;
  int E = in_sizes[1] / 2;

  char* ws = (char*)d_ws;
  size_t off = 0;
  auto alloc = [&](size_t bytes) {
    char* p = ws + off;
    off += (bytes + 255) & ~size_t(255);
    return p;
  };
  int*            edges   = (int*)alloc((size_t)2 * E * 4);
  int*            flag    = (int*)alloc(256);
  int*            deg     = (int*)alloc((size_t)N * 4);
  int*            cursor  = (int*)alloc((size_t)N * 4);
  int*            rowptr  = (int*)alloc((size_t)(N + 1) * 4);
  int*            bsum    = (int*)alloc(1024);
  int*            boff    = (int*)alloc(1024);
  int*            csr_src = (int*)alloc((size_t)E * 4);
  unsigned short* xl1b    = (unsigned short*)alloc((size_t)N * 64 * 2);
  float*          a1      = (float*)alloc((size_t)N * 16 * 4);
  unsigned short* hrb     = (unsigned short*)alloc((size_t)N * 64 * 2);
  float*          a2      = (float*)alloc((size_t)N * 16 * 4);
  float*          wl      = (float*)alloc(64 * 8 * 4);
  float*          wr      = (float*)alloc(64 * 8 * 4);
  unsigned short* Bpack   = (unsigned short*)alloc(512 * 64 * 2);
  unsigned short* gb      = (unsigned short*)alloc((size_t)N * 512 * 2);
  (void)ws_size;

  const int* srcp = edges;
  const int* dstp = edges + E;
  int SB = (N + 1 + NT - 1) / NT;   // must be <= 256

  detect_kernel<<<1, NT, 0, stream>>>((const int*)ei, flag, 2 * E);
  zero2_kernel<<<(N + NT - 1) / NT, NT, 0, stream>>>(deg, cursor, N);
  cvt_edges_kernel<<<(2 * E + NT - 1) / NT, NT, 0, stream>>>(ei, edges, flag, deg, E, 2 * E);

  // CSR build
  scan1_kernel<<<SB, NT, 0, stream>>>(deg, bsum, N);
  scan2_kernel<<<1, NT, 0, stream>>>(bsum, boff, SB);
  scan3_kernel<<<SB, NT, 0, stream>>>(deg, boff, rowptr, N);
  scatter_kernel<<<(E + NT - 1) / NT, NT, 0, stream>>>(srcp, dstp, rowptr, cursor, csr_src, E);

  // dense precomputation
  gemm1_kernel<<<(N + 31) / 32, NT, 0, stream>>>(x, W1, attl1, attr1, xl1b, a1, N);
  foldw_kernel<<<1, 512, 0, stream>>>(W2, attl2, attr2, wl, wr);
  foldB_kernel<<<(512 * 64 + NT - 1) / NT, NT, 0, stream>>>(W2, Bpack);

  // layer 1 aggregation (+ fused relu/bias)
  node_aggr1_kernel<<<(N + 3) / 4, NT, 0, stream>>>(rowptr, csr_src, a1, xl1b, b1, hrb, N);

  // layer-2 attention dots (streaming)
  a2dots_kernel<<<(N + A2N - 1) / A2N, NT, 0, stream>>>(hrb, wl, wr, a2, N);

  // layer 2 aggregation -> g (bf16), then MFMA epilogue
  node_aggr2_kernel<<<(N + 3) / 4, NT, 0, stream>>>(rowptr, csr_src, a2, hrb, gb, N);
  gemm3_mfma_kernel<<<(N + 63) / 64, NT, 0, stream>>>(gb, Bpack, b2, out, N);
}

// Round 10
// 233.721 us; speedup vs baseline: 2.0089x; 1.1528x over previous
//
#include <hip/hip_runtime.h>
#include <stdint.h>

#define NT 256

typedef __attribute__((ext_vector_type(8))) short bf16x8;
typedef __attribute__((ext_vector_type(4))) float f32x4;

__device__ __forceinline__ float lrelu(float x) { return x > 0.f ? x : 0.2f * x; }

__device__ __forceinline__ float b2f(unsigned short u) {
  union { unsigned int i; float f; } v; v.i = ((unsigned int)u) << 16; return v.f;
}
__device__ __forceinline__ unsigned short f2b(float f) {
  unsigned int u = __float_as_uint(f);
  return (unsigned short)((u + 0x7fffu + ((u >> 16) & 1u)) >> 16);   // RNE
}

// ---- edge dtype detection (int32 vs int64) ----
__global__ void detect_kernel(const int* __restrict__ ei, int* __restrict__ flag, int twoE) {
  __shared__ int any;
  if (threadIdx.x == 0) any = 0;
  __syncthreads();
  int n = twoE < 4096 ? twoE : 4096;
  for (int i = threadIdx.x * 2 + 1; i < n; i += 2 * NT)
    if (ei[i] != 0) any = 1;   // benign race, same value
  __syncthreads();
  if (threadIdx.x == 0) *flag = any;   // 1 -> int32 data, 0 -> int64
}

// ---- convert edges + fused dst histogram ----
__global__ void cvt_edges_kernel(const void* __restrict__ ei, int* __restrict__ out,
                                 const int* __restrict__ flag, int* __restrict__ deg,
                                 int E, int twoE) {
  int i = blockIdx.x * NT + threadIdx.x;
  if (i >= twoE) return;
  int v;
  if (*flag) v = ((const int*)ei)[i];
  else       v = (int)((const long long*)ei)[i];
  out[i] = v;
  if (i >= E) atomicAdd(&deg[v], 1);   // dst half
}

// ---- CSR build ----
__global__ void zero2_kernel(int* __restrict__ a, int* __restrict__ b, int n) {
  int i = blockIdx.x * NT + threadIdx.x;
  if (i < n) { a[i] = 0; b[i] = 0; }
}

__global__ void scan1_kernel(const int* __restrict__ deg, int* __restrict__ bsum, int N) {
  __shared__ int sm[NT];
  int idx = blockIdx.x * NT + threadIdx.x;
  sm[threadIdx.x] = (idx < N) ? deg[idx] : 0;
  __syncthreads();
  for (int s = NT / 2; s > 0; s >>= 1) {
    if (threadIdx.x < s) sm[threadIdx.x] += sm[threadIdx.x + s];
    __syncthreads();
  }
  if (threadIdx.x == 0) bsum[blockIdx.x] = sm[0];
}

__global__ void scan2_kernel(const int* __restrict__ bsum, int* __restrict__ boff, int SB) {
  __shared__ int sm[NT];
  int t = threadIdx.x;
  int v = (t < SB) ? bsum[t] : 0;
  sm[t] = v;
  __syncthreads();
  for (int s = 1; s < NT; s <<= 1) {
    int add = (t >= s) ? sm[t - s] : 0;
    __syncthreads();
    sm[t] += add;
    __syncthreads();
  }
  if (t < SB) boff[t] = sm[t] - v;   // exclusive
}

__global__ void scan3_kernel(const int* __restrict__ deg, const int* __restrict__ boff,
                             int* __restrict__ rowptr, int N) {
  __shared__ int sm[NT];
  int idx = blockIdx.x * NT + threadIdx.x;
  int v = (idx < N) ? deg[idx] : 0;
  sm[threadIdx.x] = v;
  __syncthreads();
  for (int s = 1; s < NT; s <<= 1) {
    int add = (threadIdx.x >= s) ? sm[threadIdx.x - s] : 0;
    __syncthreads();
    sm[threadIdx.x] += add;
    __syncthreads();
  }
  if (idx <= N) rowptr[idx] = boff[blockIdx.x] + sm[threadIdx.x] - v;  // exclusive scan
}

__global__ void scatter_kernel(const int* __restrict__ src, const int* __restrict__ dst,
                               const int* __restrict__ rowptr, int* __restrict__ cursor,
                               int* __restrict__ csr_src, int E) {
  int e = blockIdx.x * NT + threadIdx.x;
  if (e >= E) return;
  int d = dst[e];
  int pos = rowptr[d] + atomicAdd(&cursor[d], 1);
  csr_src[pos] = src[e];
}

// ---- pack W1 into MFMA B-fragment lane order (bf16):
// W1pack[((chunk*4+ct)*64 + lane)*8 + j] = bf16( W1[k*64 + col] )
//   k = chunk*32 + (lane>>4)*8 + j, col = ct*16 + (lane&15)
__global__ void foldB1_kernel(const float* __restrict__ W1, unsigned short* __restrict__ W1pack) {
  int idx = blockIdx.x * NT + threadIdx.x;   // over 128*64
  if (idx >= 128 * 64) return;
  int j = idx & 7;
  int lane = (idx >> 3) & 63;
  int ctchunk = idx >> 9;
  int ct = ctchunk & 3;
  int chunk = ctchunk >> 2;
  int k = chunk * 32 + ((lane >> 4) << 3) + j;
  int col = ct * 16 + (lane & 15);
  W1pack[idx] = f2b(W1[k * 64 + col]);
}

// ---- layer 1 MFMA GEMM + fused attention dots: xl1b = bf16(x@W1), a1 = [a_l|a_r] ----
// 4 waves/block, 16 rows/wave; A-frag = 32B contiguous x load (fp32->bf16)
__global__ void __launch_bounds__(NT)
gemm1_mfma_kernel(const float* __restrict__ x, const unsigned short* __restrict__ W1pack,
                  const float* __restrict__ attl, const float* __restrict__ attr,
                  unsigned short* __restrict__ xl1b, float* __restrict__ a1, int N) {
  int w = threadIdx.x >> 6;
  int lane = threadIdx.x & 63;
  int colb = lane & 15;
  int rgrp = lane >> 4;            // 0..3
  int row0w = blockIdx.x * 64 + w * 16;
  int arow = row0w + colb;
  if (arow >= N) arow = N - 1;     // clamp; stores guarded
  const float* ap = x + (size_t)arow * 128 + (rgrp << 3);

  f32x4 acc[4];
#pragma unroll
  for (int ct = 0; ct < 4; ++ct) { acc[ct][0] = 0.f; acc[ct][1] = 0.f; acc[ct][2] = 0.f; acc[ct][3] = 0.f; }

#pragma unroll
  for (int chunk = 0; chunk < 4; ++chunk) {
    float4 v0 = *(const float4*)(ap + chunk * 32);
    float4 v1 = *(const float4*)(ap + chunk * 32 + 4);
    bf16x8 a;
    a[0] = (short)f2b(v0.x); a[1] = (short)f2b(v0.y);
    a[2] = (short)f2b(v0.z); a[3] = (short)f2b(v0.w);
    a[4] = (short)f2b(v1.x); a[5] = (short)f2b(v1.y);
    a[6] = (short)f2b(v1.z); a[7] = (short)f2b(v1.w);
    const unsigned short* bp = W1pack + ((size_t)chunk * 4 * 64 + lane) * 8;
#pragma unroll
    for (int ct = 0; ct < 4; ++ct) {
      bf16x8 b = *(const bf16x8*)(bp + (size_t)ct * 64 * 8);
      acc[ct] = __builtin_amdgcn_mfma_f32_16x16x32_bf16(a, b, acc[ct], 0, 0, 0);
    }
  }

  // epilogue: store xl1b + reduce attention dots from C-fragment layout
  // C: lane holds acc[ct][r] = xl1[row0w + rgrp*4 + r][ct*16 + colb]
#pragma unroll
  for (int ct = 0; ct < 4; ++ct) {
    float attlc = attl[ct * 16 + colb];
    float attrc = attr[ct * 16 + colb];
    int h = ct * 2 + (colb >> 3);
#pragma unroll
    for (int r = 0; r < 4; ++r) {
      int n = row0w + rgrp * 4 + r;
      float v = acc[ct][r];
      if (n < N) xl1b[(size_t)n * 64 + ct * 16 + colb] = f2b(v);
      float pl = v * attlc;
      float pr = v * attrc;
      pl += __shfl_xor(pl, 1, 64); pr += __shfl_xor(pr, 1, 64);
      pl += __shfl_xor(pl, 2, 64); pr += __shfl_xor(pr, 2, 64);
      pl += __shfl_xor(pl, 4, 64); pr += __shfl_xor(pr, 4, 64);
      if ((lane & 7) == 0 && n < N) {
        a1[n * 16 + h] = pl;
        a1[n * 16 + 8 + h] = pr;
      }
    }
  }
}

// ---- fold W2 with att vectors ----
__global__ void foldw_kernel(const float* __restrict__ W2, const float* __restrict__ attl2,
                             const float* __restrict__ attr2, float* __restrict__ wl,
                             float* __restrict__ wr) {
  int t = threadIdx.x;           // 0..511
  int k = t >> 3, h = t & 7;
  float sl = 0.f, sr = 0.f;
  for (int f = 0; f < 64; ++f) {
    float w = W2[k * 512 + h * 64 + f];
    sl += w * attl2[h * 64 + f];
    sr += w * attr2[h * 64 + f];
  }
  wl[k * 8 + h] = sl;
  wr[k * 8 + h] = sr;
}

// ---- pack B fragments for MFMA epilogue (layer-2 W2, head-mean folded) ----
__global__ void foldB_kernel(const float* __restrict__ W2, unsigned short* __restrict__ Bpack) {
  int idx = blockIdx.x * NT + threadIdx.x;   // over 512*64
  if (idx >= 512 * 64) return;
  int j = idx & 7;
  int lane = (idx >> 3) & 63;
  int ctchunk = idx >> 9;
  int ct = ctchunk & 3;
  int chunk = ctchunk >> 2;
  int hk = chunk * 32 + ((lane >> 4) << 3) + j;
  int h = hk >> 6, kk = hk & 63;
  int f = ct * 16 + (lane & 15);
  Bpack[idx] = f2b(W2[kk * 512 + h * 64 + f] * 0.125f);
}

// ---- layer1: single-pass softmax+aggregation, all-lane staging, no butterflies ----
__global__ void __launch_bounds__(NT)
node_aggr1_kernel(const int* __restrict__ rowptr, const int* __restrict__ csr_src,
                  const float* __restrict__ a1, const unsigned short* __restrict__ xl1b,
                  const float* __restrict__ b1, unsigned short* __restrict__ hrb, int N) {
  __shared__ float ps[4][64][8];
  __shared__ int ss[4][64];
  int w = threadIdx.x >> 6;
  int n = blockIdx.x * 4 + w;
  if (n >= N) return;
  int lane = threadIdx.x & 63;
  int hstage = lane & 7;
  int j8 = lane >> 3;
  int hown = lane >> 3;
  int base = rowptr[n];
  int deg = rowptr[n + 1] - base;

  float arh = a1[n * 16 + 8 + hstage];
  const unsigned short* xp = xl1b + lane;
  float acc = 0.f, dn = 0.f;

  for (int j0 = 0; j0 < deg; j0 += 64) {
    int cnt = deg - j0; if (cnt > 64) cnt = 64;
    if (lane < cnt) ss[w][lane] = csr_src[base + j0 + lane];
    asm volatile("s_waitcnt lgkmcnt(0)" ::: "memory");
    for (int jj = 0; jj < cnt; jj += 8) {
      int j = jj + j8;
      if (j < cnt) {
        int s = ss[w][j];
        float p = __expf(lrelu(a1[(unsigned)s * 16 + hstage] + arh));
        ps[w][j][hstage] = p;
      }
    }
    asm volatile("s_waitcnt lgkmcnt(0)" ::: "memory");
    int j = 0;
    for (; j + 4 <= cnt; j += 4) {
      int s0 = ss[w][j+0], s1 = ss[w][j+1], s2 = ss[w][j+2], s3 = ss[w][j+3];
      float p0 = ps[w][j+0][hown], p1 = ps[w][j+1][hown];
      float p2 = ps[w][j+2][hown], p3 = ps[w][j+3][hown];
      float v0 = b2f(xp[(unsigned)s0 * 64]), v1 = b2f(xp[(unsigned)s1 * 64]);
      float v2 = b2f(xp[(unsigned)s2 * 64]), v3 = b2f(xp[(unsigned)s3 * 64]);
      dn += (p0 + p1) + (p2 + p3);
      acc += p0 * v0 + p1 * v1 + p2 * v2 + p3 * v3;
    }
    for (; j < cnt; ++j) {
      int s = ss[w][j];
      float p = ps[w][j][hown];
      dn += p;
      acc += p * b2f(xp[(unsigned)s * 64]);
    }
  }
  acc = acc / (dn + 1e-16f);
  float hv = fmaxf(acc + b1[lane], 0.f);   // relu(out1 + b1)
  hrb[(size_t)n * 64 + lane] = f2b(hv);
}

// ---- layer-2 attention dots as a streaming kernel ----
#define A2N 256
__global__ void __launch_bounds__(NT)
a2dots_kernel(const unsigned short* __restrict__ hrb, const float* __restrict__ wl,
              const float* __restrict__ wr, float* __restrict__ a2, int N) {
  __shared__ unsigned short hs[A2N][65];
  __shared__ float wls[64 * 8], wrs[64 * 8];
  int tid = threadIdx.x;
  int n0 = blockIdx.x * A2N;
  for (int i = tid; i < 512; i += NT) { wls[i] = wl[i]; wrs[i] = wr[i]; }
  for (int i = tid; i < A2N * 8; i += NT) {
    int r = i >> 3, seg = i & 7;
    int n = n0 + r;
    uint4 v = make_uint4(0, 0, 0, 0);
    if (n < N) v = *(const uint4*)&hrb[(size_t)n * 64 + seg * 8];
    int c = seg * 8;
    hs[r][c + 0] = (unsigned short)(v.x);
    hs[r][c + 1] = (unsigned short)(v.x >> 16);
    hs[r][c + 2] = (unsigned short)(v.y);
    hs[r][c + 3] = (unsigned short)(v.y >> 16);
    hs[r][c + 4] = (unsigned short)(v.z);
    hs[r][c + 5] = (unsigned short)(v.z >> 16);
    hs[r][c + 6] = (unsigned short)(v.w);
    hs[r][c + 7] = (unsigned short)(v.w >> 16);
  }
  __syncthreads();
  float tl[8], tr[8];
#pragma unroll
  for (int h = 0; h < 8; ++h) { tl[h] = 0.f; tr[h] = 0.f; }
#pragma unroll 4
  for (int k = 0; k < 64; ++k) {
    float hv = b2f(hs[tid][k]);
    float4 l0 = *(const float4*)&wls[k * 8];
    float4 l1 = *(const float4*)&wls[k * 8 + 4];
    float4 r0 = *(const float4*)&wrs[k * 8];
    float4 r1 = *(const float4*)&wrs[k * 8 + 4];
    tl[0] += hv * l0.x; tl[1] += hv * l0.y; tl[2] += hv * l0.z; tl[3] += hv * l0.w;
    tl[4] += hv * l1.x; tl[5] += hv * l1.y; tl[6] += hv * l1.z; tl[7] += hv * l1.w;
    tr[0] += hv * r0.x; tr[1] += hv * r0.y; tr[2] += hv * r0.z; tr[3] += hv * r0.w;
    tr[4] += hv * r1.x; tr[5] += hv * r1.y; tr[6] += hv * r1.z; tr[7] += hv * r1.w;
  }
  int n = n0 + tid;
  if (n < N) {
    *(float4*)&a2[n * 16 + 0]  = make_float4(tl[0], tl[1], tl[2], tl[3]);
    *(float4*)&a2[n * 16 + 4]  = make_float4(tl[4], tl[5], tl[6], tl[7]);
    *(float4*)&a2[n * 16 + 8]  = make_float4(tr[0], tr[1], tr[2], tr[3]);
    *(float4*)&a2[n * 16 + 12] = make_float4(tr[4], tr[5], tr[6], tr[7]);
  }
}

// ---- layer2: single-pass softmax+aggregation -> normalized g (bf16) ----
__global__ void __launch_bounds__(NT)
node_aggr2_kernel(const int* __restrict__ rowptr, const int* __restrict__ csr_src,
                  const float* __restrict__ a2, const unsigned short* __restrict__ hrb,
                  unsigned short* __restrict__ gb, int N) {
  __shared__ float ps[4][64][8];
  __shared__ int ss[4][64];
  int w = threadIdx.x >> 6;
  int n = blockIdx.x * 4 + w;
  if (n >= N) return;
  int lane = threadIdx.x & 63;
  int hstage = lane & 7;
  int j8 = lane >> 3;
  int base = rowptr[n];
  int deg = rowptr[n + 1] - base;

  float arh = a2[n * 16 + 8 + hstage];
  const unsigned short* hp = hrb + lane;
  float acc[8] = {0.f, 0.f, 0.f, 0.f, 0.f, 0.f, 0.f, 0.f};
  float dn_own = 0.f;

  for (int j0 = 0; j0 < deg; j0 += 64) {
    int cnt = deg - j0; if (cnt > 64) cnt = 64;
    if (lane < cnt) ss[w][lane] = csr_src[base + j0 + lane];
    asm volatile("s_waitcnt lgkmcnt(0)" ::: "memory");
    for (int jj = 0; jj < cnt; jj += 8) {
      int j = jj + j8;
      if (j < cnt) {
        int s = ss[w][j];
        float p = __expf(lrelu(a2[(unsigned)s * 16 + hstage] + arh));
        ps[w][j][hstage] = p;
      }
    }
    asm volatile("s_waitcnt lgkmcnt(0)" ::: "memory");
    for (int j = 0; j < cnt; ++j) {
      int s = ss[w][j];
      float hv = b2f(hp[(unsigned)s * 64]);
      float4 pa = *(const float4*)&ps[w][j][0];
      float4 pb = *(const float4*)&ps[w][j][4];
      dn_own += ps[w][j][hstage];
      acc[0] += pa.x * hv; acc[1] += pa.y * hv; acc[2] += pa.z * hv; acc[3] += pa.w * hv;
      acc[4] += pb.x * hv; acc[5] += pb.y * hv; acc[6] += pb.z * hv; acc[7] += pb.w * hv;
    }
  }
#pragma unroll
  for (int h = 0; h < 8; ++h) {
    float dnh = __shfl(dn_own, h, 64);
    float v = acc[h] * (1.f / (dnh + 1e-16f));
    gb[(size_t)n * 512 + h * 64 + lane] = f2b(v);
  }
}

// ---- MFMA epilogue GEMM: out[N,64] = gb[N,512](bf16) @ Bpack + b2 ----
__global__ void __launch_bounds__(NT)
gemm3_mfma_kernel(const unsigned short* __restrict__ gb,
                  const unsigned short* __restrict__ Bpack,
                  const float* __restrict__ b2, float* __restrict__ out, int N) {
  int w = threadIdx.x >> 6;
  int lane = threadIdx.x & 63;
  int row0w = blockIdx.x * 64 + w * 16;
  int arow = row0w + (lane & 15);
  if (arow >= N) arow = N - 1;          // clamp (stores are guarded)
  const unsigned short* ap = gb + (size_t)arow * 512 + ((lane >> 4) << 3);

  f32x4 acc[4];
#pragma unroll
  for (int ct = 0; ct < 4; ++ct) {
    float bb = b2[ct * 16 + (lane & 15)];
    acc[ct][0] = bb; acc[ct][1] = bb; acc[ct][2] = bb; acc[ct][3] = bb;
  }

#pragma unroll 4
  for (int chunk = 0; chunk < 16; ++chunk) {
    bf16x8 a = *(const bf16x8*)(ap + chunk * 32);
    const unsigned short* bp = Bpack + ((size_t)chunk * 4 * 64 + lane) * 8;
#pragma unroll
    for (int ct = 0; ct < 4; ++ct) {
      bf16x8 b = *(const bf16x8*)(bp + (size_t)ct * 64 * 8);
      acc[ct] = __builtin_amdgcn_mfma_f32_16x16x32_bf16(a, b, acc[ct], 0, 0, 0);
    }
  }

  int orow0 = row0w + ((lane >> 4) << 2);
#pragma unroll
  for (int ct = 0; ct < 4; ++ct) {
    int col = ct * 16 + (lane & 15);
#pragma unroll
    for (int r = 0; r < 4; ++r) {
      int n = orow0 + r;
      if (n < N) out[(size_t)n * 64 + col] = acc[ct][r];
    }
  }
}

extern "C" void kernel_launch(void* const* d_in, const int* in_sizes, int n_in,
                              void* d_out, int out_size, void* d_ws, size_t ws_size,
                              hipStream_t stream) {
  const float* x     = (const float*)d_in[0];
  const void*  ei    = d_in[1];
  const float* W1    = (const float*)d_in[2];
  const float* attl1 = (const float*)d_in[3];
  const float* attr1 = (const float*)d_in[4];
  const float* b1    = (const float*)d_in[5];
  const float* W2    = (const float*)d_in[6];
  const float* attl2 = (const float*)d_in[7];
  const float* attr2 = (const float*)d_in[8];
  const float* b2    = (const float*)d_in[9];
  float* out = (float*)d_out;

  int N = in_sizes[0] / 128;
  int E = in_sizes[1] / 2;

  char* ws = (char*)d_ws;
  size_t off = 0;
  auto alloc = [&](size_t bytes) {
    char* p = ws + off;
    off += (bytes + 255) & ~size_t(255);
    return p;
  };
  int*            edges   = (int*)alloc((size_t)2 * E * 4);
  int*            flag    = (int*)alloc(256);
  int*            deg     = (int*)alloc((size_t)N * 4);
  int*            cursor  = (int*)alloc((size_t)N * 4);
  int*            rowptr  = (int*)alloc((size_t)(N + 1) * 4);
  int*            bsum    = (int*)alloc(1024);
  int*            boff    = (int*)alloc(1024);
  int*            csr_src = (int*)alloc((size_t)E * 4);
  unsigned short* xl1b    = (unsigned short*)alloc((size_t)N * 64 * 2);
  float*          a1      = (float*)alloc((size_t)N * 16 * 4);
  unsigned short* hrb     = (unsigned short*)alloc((size_t)N * 64 * 2);
  float*          a2      = (float*)alloc((size_t)N * 16 * 4);
  float*          wl      = (float*)alloc(64 * 8 * 4);
  float*          wr      = (float*)alloc(64 * 8 * 4);
  unsigned short* Bpack   = (unsigned short*)alloc(512 * 64 * 2);
  unsigned short* W1pack  = (unsigned short*)alloc(128 * 64 * 2);
  unsigned short* gb      = (unsigned short*)alloc((size_t)N * 512 * 2);
  (void)ws_size;

  const int* srcp = edges;
  const int* dstp = edges + E;
  int SB = (N + 1 + NT - 1) / NT;   // must be <= 256

  detect_kernel<<<1, NT, 0, stream>>>((const int*)ei, flag, 2 * E);
  zero2_kernel<<<(N + NT - 1) / NT, NT, 0, stream>>>(deg, cursor, N);
  cvt_edges_kernel<<<(2 * E + NT - 1) / NT, NT, 0, stream>>>(ei, edges, flag, deg, E, 2 * E);

  // CSR build
  scan1_kernel<<<SB, NT, 0, stream>>>(deg, bsum, N);
  scan2_kernel<<<1, NT, 0, stream>>>(bsum, boff, SB);
  scan3_kernel<<<SB, NT, 0, stream>>>(deg, boff, rowptr, N);
  scatter_kernel<<<(E + NT - 1) / NT, NT, 0, stream>>>(srcp, dstp, rowptr, cursor, csr_src, E);

  // dense precomputation
  foldB1_kernel<<<(128 * 64 + NT - 1) / NT, NT, 0, stream>>>(W1, W1pack);
  gemm1_mfma_kernel<<<(N + 63) / 64, NT, 0, stream>>>(x, W1pack, attl1, attr1, xl1b, a1, N);
  foldw_kernel<<<1, 512, 0, stream>>>(W2, attl2, attr2, wl, wr);
  foldB_kernel<<<(512 * 64 + NT - 1) / NT, NT, 0, stream>>>(W2, Bpack);

  // layer 1 aggregation (+ fused relu/bias)
  node_aggr1_kernel<<<(N + 3) / 4, NT, 0, stream>>>(rowptr, csr_src, a1, xl1b, b1, hrb, N);

  // layer-2 attention dots (streaming)
  a2dots_kernel<<<(N + A2N - 1) / A2N, NT, 0, stream>>>(hrb, wl, wr, a2, N);

  // layer 2 aggregation -> g (bf16), then MFMA epilogue
  node_aggr2_kernel<<<(N + 3) / 4, NT, 0, stream>>>(rowptr, csr_src, a2, hrb, gb, N);
  gemm3_mfma_kernel<<<(N + 63) / 64, NT, 0, stream>>>(gb, Bpack, b2, out, N);
}

// Round 11
// 219.626 us; speedup vs baseline: 2.1378x; 1.0642x over previous
//
#include <hip/hip_runtime.h>
#include <stdint.h>

#define NT 256
#define CHUNK 4096
#define BSHIFT 8

typedef __attribute__((ext_vector_type(8))) short bf16x8;
typedef __attribute__((ext_vector_type(4))) float f32x4;

__device__ __forceinline__ float lrelu(float x) { return x > 0.f ? x : 0.2f * x; }

__device__ __forceinline__ float b2f(unsigned short u) {
  union { unsigned int i; float f; } v; v.i = ((unsigned int)u) << 16; return v.f;
}
__device__ __forceinline__ unsigned short f2b(float f) {
  unsigned int u = __float_as_uint(f);
  return (unsigned short)((u + 0x7fffu + ((u >> 16) & 1u)) >> 16);   // RNE
}

// ---- edge dtype detection (int32 vs int64) ----
__global__ void detect_kernel(const int* __restrict__ ei, int* __restrict__ flag, int twoE) {
  __shared__ int any;
  if (threadIdx.x == 0) any = 0;
  __syncthreads();
  int n = twoE < 4096 ? twoE : 4096;
  for (int i = threadIdx.x * 2 + 1; i < n; i += 2 * NT)
    if (ei[i] != 0) any = 1;   // benign race, same value
  __syncthreads();
  if (threadIdx.x == 0) *flag = any;   // 1 -> int32 data, 0 -> int64
}

// ---- convert edges (pure) ----
__global__ void cvt_edges_kernel(const void* __restrict__ ei, int* __restrict__ out,
                                 const int* __restrict__ flag, int twoE) {
  int i = blockIdx.x * NT + threadIdx.x;
  if (i >= twoE) return;
  if (*flag) out[i] = ((const int*)ei)[i];
  else       out[i] = (int)((const long long*)ei)[i];
}

__global__ void zero2_kernel(int* __restrict__ a, int* __restrict__ b, int n) {
  int i = blockIdx.x * NT + threadIdx.x;
  if (i < n) { a[i] = 0; b[i] = 0; }
}

// ---- generic scan trio (exclusive scan of in[0..n) into out[0..n]) ----
__global__ void scan1_kernel(const int* __restrict__ in, int* __restrict__ bsum, int n) {
  __shared__ int sm[NT];
  int idx = blockIdx.x * NT + threadIdx.x;
  sm[threadIdx.x] = (idx < n) ? in[idx] : 0;
  __syncthreads();
  for (int s = NT / 2; s > 0; s >>= 1) {
    if (threadIdx.x < s) sm[threadIdx.x] += sm[threadIdx.x + s];
    __syncthreads();
  }
  if (threadIdx.x == 0) bsum[blockIdx.x] = sm[0];
}

__global__ void scan2_kernel(const int* __restrict__ bsum, int* __restrict__ boff, int SB) {
  __shared__ int sm[NT];
  int t = threadIdx.x;
  int v = (t < SB) ? bsum[t] : 0;
  sm[t] = v;
  __syncthreads();
  for (int s = 1; s < NT; s <<= 1) {
    int add = (t >= s) ? sm[t - s] : 0;
    __syncthreads();
    sm[t] += add;
    __syncthreads();
  }
  if (t < SB) boff[t] = sm[t] - v;   // exclusive
}

__global__ void scan3_kernel(const int* __restrict__ in, const int* __restrict__ boff,
                             int* __restrict__ out, int n) {
  __shared__ int sm[NT];
  int idx = blockIdx.x * NT + threadIdx.x;
  int v = (idx < n) ? in[idx] : 0;
  sm[threadIdx.x] = v;
  __syncthreads();
  for (int s = 1; s < NT; s <<= 1) {
    int add = (threadIdx.x >= s) ? sm[threadIdx.x - s] : 0;
    __syncthreads();
    sm[threadIdx.x] += add;
    __syncthreads();
  }
  if (idx <= n) out[idx] = boff[blockIdx.x] + sm[threadIdx.x] - v;  // exclusive
}

// ---- phase A1: per-block bucket histogram ----
__global__ void bincount_kernel(const int* __restrict__ dst, int* __restrict__ blkcnt,
                                int E, int nblk, int nbk) {
  __shared__ int cnt[256];
  int b = blockIdx.x;
  for (int i = threadIdx.x; i < nbk; i += NT) cnt[i] = 0;
  __syncthreads();
  int beg = b * CHUNK;
  int end = beg + CHUNK < E ? beg + CHUNK : E;
  for (int i = beg + threadIdx.x; i < end; i += NT)
    atomicAdd(&cnt[dst[i] >> BSHIFT], 1);
  __syncthreads();
  for (int i = threadIdx.x; i < nbk; i += NT) blkcnt[i * nblk + b] = cnt[i];
}

// ---- phase A2: bucket-contiguous write of packed (dst,src) ----
__global__ void binwrite_kernel(const int* __restrict__ src, const int* __restrict__ dst,
                                const int* __restrict__ base, long long* __restrict__ binned,
                                int E, int nblk, int nbk) {
  __shared__ int cnt[256];
  int b = blockIdx.x;
  for (int i = threadIdx.x; i < nbk; i += NT) cnt[i] = base[i * nblk + b];
  __syncthreads();
  int beg = b * CHUNK;
  int end = beg + CHUNK < E ? beg + CHUNK : E;
  for (int i = beg + threadIdx.x; i < end; i += NT) {
    int d = dst[i];
    int pos = atomicAdd(&cnt[d >> BSHIFT], 1);
    binned[pos] = ((long long)d << 32) | (unsigned int)src[i];
  }
}

// ---- degree histogram from binned (bucket-local atomics) ----
__global__ void deghist_kernel(const long long* __restrict__ binned, int* __restrict__ deg, int E) {
  int e = blockIdx.x * NT + threadIdx.x;
  if (e < E) atomicAdd(&deg[(int)(binned[e] >> 32)], 1);
}

// ---- phase B: locality-friendly scatter to CSR ----
__global__ void scatter2_kernel(const long long* __restrict__ binned, const int* __restrict__ rowptr,
                                int* __restrict__ cursor, int* __restrict__ csr_src, int E) {
  int e = blockIdx.x * NT + threadIdx.x;
  if (e >= E) return;
  long long v = binned[e];
  int d = (int)(v >> 32);
  int s = (int)(v & 0xffffffffLL);
  int pos = rowptr[d] + atomicAdd(&cursor[d], 1);
  csr_src[pos] = s;
}

// ---- pack W1 into MFMA B-fragment lane order (bf16) ----
__global__ void foldB1_kernel(const float* __restrict__ W1, unsigned short* __restrict__ W1pack) {
  int idx = blockIdx.x * NT + threadIdx.x;   // over 128*64
  if (idx >= 128 * 64) return;
  int j = idx & 7;
  int lane = (idx >> 3) & 63;
  int ctchunk = idx >> 9;
  int ct = ctchunk & 3;
  int chunk = ctchunk >> 2;
  int k = chunk * 32 + ((lane >> 4) << 3) + j;
  int col = ct * 16 + (lane & 15);
  W1pack[idx] = f2b(W1[k * 64 + col]);
}

// ---- layer 1 MFMA GEMM + fused attention dots ----
__global__ void __launch_bounds__(NT)
gemm1_mfma_kernel(const float* __restrict__ x, const unsigned short* __restrict__ W1pack,
                  const float* __restrict__ attl, const float* __restrict__ attr,
                  unsigned short* __restrict__ xl1b, float* __restrict__ a1, int N) {
  int w = threadIdx.x >> 6;
  int lane = threadIdx.x & 63;
  int colb = lane & 15;
  int rgrp = lane >> 4;            // 0..3
  int row0w = blockIdx.x * 64 + w * 16;
  int arow = row0w + colb;
  if (arow >= N) arow = N - 1;     // clamp; stores guarded
  const float* ap = x + (size_t)arow * 128 + (rgrp << 3);

  f32x4 acc[4];
#pragma unroll
  for (int ct = 0; ct < 4; ++ct) { acc[ct][0] = 0.f; acc[ct][1] = 0.f; acc[ct][2] = 0.f; acc[ct][3] = 0.f; }

#pragma unroll
  for (int chunk = 0; chunk < 4; ++chunk) {
    float4 v0 = *(const float4*)(ap + chunk * 32);
    float4 v1 = *(const float4*)(ap + chunk * 32 + 4);
    bf16x8 a;
    a[0] = (short)f2b(v0.x); a[1] = (short)f2b(v0.y);
    a[2] = (short)f2b(v0.z); a[3] = (short)f2b(v0.w);
    a[4] = (short)f2b(v1.x); a[5] = (short)f2b(v1.y);
    a[6] = (short)f2b(v1.z); a[7] = (short)f2b(v1.w);
    const unsigned short* bp = W1pack + ((size_t)chunk * 4 * 64 + lane) * 8;
#pragma unroll
    for (int ct = 0; ct < 4; ++ct) {
      bf16x8 b = *(const bf16x8*)(bp + (size_t)ct * 64 * 8);
      acc[ct] = __builtin_amdgcn_mfma_f32_16x16x32_bf16(a, b, acc[ct], 0, 0, 0);
    }
  }

#pragma unroll
  for (int ct = 0; ct < 4; ++ct) {
    float attlc = attl[ct * 16 + colb];
    float attrc = attr[ct * 16 + colb];
    int h = ct * 2 + (colb >> 3);
#pragma unroll
    for (int r = 0; r < 4; ++r) {
      int n = row0w + rgrp * 4 + r;
      float v = acc[ct][r];
      if (n < N) xl1b[(size_t)n * 64 + ct * 16 + colb] = f2b(v);
      float pl = v * attlc;
      float pr = v * attrc;
      pl += __shfl_xor(pl, 1, 64); pr += __shfl_xor(pr, 1, 64);
      pl += __shfl_xor(pl, 2, 64); pr += __shfl_xor(pr, 2, 64);
      pl += __shfl_xor(pl, 4, 64); pr += __shfl_xor(pr, 4, 64);
      if ((lane & 7) == 0 && n < N) {
        a1[n * 16 + h] = pl;
        a1[n * 16 + 8 + h] = pr;
      }
    }
  }
}

// ---- fold W2 with att vectors ----
__global__ void foldw_kernel(const float* __restrict__ W2, const float* __restrict__ attl2,
                             const float* __restrict__ attr2, float* __restrict__ wl,
                             float* __restrict__ wr) {
  int t = threadIdx.x;           // 0..511
  int k = t >> 3, h = t & 7;
  float sl = 0.f, sr = 0.f;
  for (int f = 0; f < 64; ++f) {
    float w = W2[k * 512 + h * 64 + f];
    sl += w * attl2[h * 64 + f];
    sr += w * attr2[h * 64 + f];
  }
  wl[k * 8 + h] = sl;
  wr[k * 8 + h] = sr;
}

// ---- pack B fragments for MFMA epilogue (layer-2 W2, head-mean folded) ----
__global__ void foldB_kernel(const float* __restrict__ W2, unsigned short* __restrict__ Bpack) {
  int idx = blockIdx.x * NT + threadIdx.x;   // over 512*64
  if (idx >= 512 * 64) return;
  int j = idx & 7;
  int lane = (idx >> 3) & 63;
  int ctchunk = idx >> 9;
  int ct = ctchunk & 3;
  int chunk = ctchunk >> 2;
  int hk = chunk * 32 + ((lane >> 4) << 3) + j;
  int h = hk >> 6, kk = hk & 63;
  int f = ct * 16 + (lane & 15);
  Bpack[idx] = f2b(W2[kk * 512 + h * 64 + f] * 0.125f);
}

// ---- layer1: single-pass softmax+aggregation ----
__global__ void __launch_bounds__(NT)
node_aggr1_kernel(const int* __restrict__ rowptr, const int* __restrict__ csr_src,
                  const float* __restrict__ a1, const unsigned short* __restrict__ xl1b,
                  const float* __restrict__ b1, unsigned short* __restrict__ hrb, int N) {
  __shared__ float ps[4][64][8];
  __shared__ int ss[4][64];
  int w = threadIdx.x >> 6;
  int n = blockIdx.x * 4 + w;
  if (n >= N) return;
  int lane = threadIdx.x & 63;
  int hstage = lane & 7;
  int j8 = lane >> 3;
  int hown = lane >> 3;
  int base = rowptr[n];
  int deg = rowptr[n + 1] - base;

  float arh = a1[n * 16 + 8 + hstage];
  const unsigned short* xp = xl1b + lane;
  float acc = 0.f, dn = 0.f;

  for (int j0 = 0; j0 < deg; j0 += 64) {
    int cnt = deg - j0; if (cnt > 64) cnt = 64;
    if (lane < cnt) ss[w][lane] = csr_src[base + j0 + lane];
    asm volatile("s_waitcnt lgkmcnt(0)" ::: "memory");
    for (int jj = 0; jj < cnt; jj += 8) {
      int j = jj + j8;
      if (j < cnt) {
        int s = ss[w][j];
        float p = __expf(lrelu(a1[(unsigned)s * 16 + hstage] + arh));
        ps[w][j][hstage] = p;
      }
    }
    asm volatile("s_waitcnt lgkmcnt(0)" ::: "memory");
    int j = 0;
    for (; j + 4 <= cnt; j += 4) {
      int s0 = ss[w][j+0], s1 = ss[w][j+1], s2 = ss[w][j+2], s3 = ss[w][j+3];
      float p0 = ps[w][j+0][hown], p1 = ps[w][j+1][hown];
      float p2 = ps[w][j+2][hown], p3 = ps[w][j+3][hown];
      float v0 = b2f(xp[(unsigned)s0 * 64]), v1 = b2f(xp[(unsigned)s1 * 64]);
      float v2 = b2f(xp[(unsigned)s2 * 64]), v3 = b2f(xp[(unsigned)s3 * 64]);
      dn += (p0 + p1) + (p2 + p3);
      acc += p0 * v0 + p1 * v1 + p2 * v2 + p3 * v3;
    }
    for (; j < cnt; ++j) {
      int s = ss[w][j];
      float p = ps[w][j][hown];
      dn += p;
      acc += p * b2f(xp[(unsigned)s * 64]);
    }
  }
  acc = acc / (dn + 1e-16f);
  float hv = fmaxf(acc + b1[lane], 0.f);   // relu(out1 + b1)
  hrb[(size_t)n * 64 + lane] = f2b(hv);
}

// ---- layer-2 attention dots as a streaming kernel ----
#define A2N 256
__global__ void __launch_bounds__(NT)
a2dots_kernel(const unsigned short* __restrict__ hrb, const float* __restrict__ wl,
              const float* __restrict__ wr, float* __restrict__ a2, int N) {
  __shared__ unsigned short hs[A2N][65];
  __shared__ float wls[64 * 8], wrs[64 * 8];
  int tid = threadIdx.x;
  int n0 = blockIdx.x * A2N;
  for (int i = tid; i < 512; i += NT) { wls[i] = wl[i]; wrs[i] = wr[i]; }
  for (int i = tid; i < A2N * 8; i += NT) {
    int r = i >> 3, seg = i & 7;
    int n = n0 + r;
    uint4 v = make_uint4(0, 0, 0, 0);
    if (n < N) v = *(const uint4*)&hrb[(size_t)n * 64 + seg * 8];
    int c = seg * 8;
    hs[r][c + 0] = (unsigned short)(v.x);
    hs[r][c + 1] = (unsigned short)(v.x >> 16);
    hs[r][c + 2] = (unsigned short)(v.y);
    hs[r][c + 3] = (unsigned short)(v.y >> 16);
    hs[r][c + 4] = (unsigned short)(v.z);
    hs[r][c + 5] = (unsigned short)(v.z >> 16);
    hs[r][c + 6] = (unsigned short)(v.w);
    hs[r][c + 7] = (unsigned short)(v.w >> 16);
  }
  __syncthreads();
  float tl[8], tr[8];
#pragma unroll
  for (int h = 0; h < 8; ++h) { tl[h] = 0.f; tr[h] = 0.f; }
#pragma unroll 4
  for (int k = 0; k < 64; ++k) {
    float hv = b2f(hs[tid][k]);
    float4 l0 = *(const float4*)&wls[k * 8];
    float4 l1 = *(const float4*)&wls[k * 8 + 4];
    float4 r0 = *(const float4*)&wrs[k * 8];
    float4 r1 = *(const float4*)&wrs[k * 8 + 4];
    tl[0] += hv * l0.x; tl[1] += hv * l0.y; tl[2] += hv * l0.z; tl[3] += hv * l0.w;
    tl[4] += hv * l1.x; tl[5] += hv * l1.y; tl[6] += hv * l1.z; tl[7] += hv * l1.w;
    tr[0] += hv * r0.x; tr[1] += hv * r0.y; tr[2] += hv * r0.z; tr[3] += hv * r0.w;
    tr[4] += hv * r1.x; tr[5] += hv * r1.y; tr[6] += hv * r1.z; tr[7] += hv * r1.w;
  }
  int n = n0 + tid;
  if (n < N) {
    *(float4*)&a2[n * 16 + 0]  = make_float4(tl[0], tl[1], tl[2], tl[3]);
    *(float4*)&a2[n * 16 + 4]  = make_float4(tl[4], tl[5], tl[6], tl[7]);
    *(float4*)&a2[n * 16 + 8]  = make_float4(tr[0], tr[1], tr[2], tr[3]);
    *(float4*)&a2[n * 16 + 12] = make_float4(tr[4], tr[5], tr[6], tr[7]);
  }
}

// ---- layer2: single-pass softmax+aggregation -> normalized g (bf16) ----
__global__ void __launch_bounds__(NT)
node_aggr2_kernel(const int* __restrict__ rowptr, const int* __restrict__ csr_src,
                  const float* __restrict__ a2, const unsigned short* __restrict__ hrb,
                  unsigned short* __restrict__ gb, int N) {
  __shared__ float ps[4][64][8];
  __shared__ int ss[4][64];
  int w = threadIdx.x >> 6;
  int n = blockIdx.x * 4 + w;
  if (n >= N) return;
  int lane = threadIdx.x & 63;
  int hstage = lane & 7;
  int j8 = lane >> 3;
  int base = rowptr[n];
  int deg = rowptr[n + 1] - base;

  float arh = a2[n * 16 + 8 + hstage];
  const unsigned short* hp = hrb + lane;
  float acc[8] = {0.f, 0.f, 0.f, 0.f, 0.f, 0.f, 0.f, 0.f};
  float dn_own = 0.f;

  for (int j0 = 0; j0 < deg; j0 += 64) {
    int cnt = deg - j0; if (cnt > 64) cnt = 64;
    if (lane < cnt) ss[w][lane] = csr_src[base + j0 + lane];
    asm volatile("s_waitcnt lgkmcnt(0)" ::: "memory");
    for (int jj = 0; jj < cnt; jj += 8) {
      int j = jj + j8;
      if (j < cnt) {
        int s = ss[w][j];
        float p = __expf(lrelu(a2[(unsigned)s * 16 + hstage] + arh));
        ps[w][j][hstage] = p;
      }
    }
    asm volatile("s_waitcnt lgkmcnt(0)" ::: "memory");
    for (int j = 0; j < cnt; ++j) {
      int s = ss[w][j];
      float hv = b2f(hp[(unsigned)s * 64]);
      float4 pa = *(const float4*)&ps[w][j][0];
      float4 pb = *(const float4*)&ps[w][j][4];
      dn_own += ps[w][j][hstage];
      acc[0] += pa.x * hv; acc[1] += pa.y * hv; acc[2] += pa.z * hv; acc[3] += pa.w * hv;
      acc[4] += pb.x * hv; acc[5] += pb.y * hv; acc[6] += pb.z * hv; acc[7] += pb.w * hv;
    }
  }
#pragma unroll
  for (int h = 0; h < 8; ++h) {
    float dnh = __shfl(dn_own, h, 64);
    float v = acc[h] * (1.f / (dnh + 1e-16f));
    gb[(size_t)n * 512 + h * 64 + lane] = f2b(v);
  }
}

// ---- MFMA epilogue GEMM: out[N,64] = gb[N,512](bf16) @ Bpack + b2 ----
__global__ void __launch_bounds__(NT)
gemm3_mfma_kernel(const unsigned short* __restrict__ gb,
                  const unsigned short* __restrict__ Bpack,
                  const float* __restrict__ b2, float* __restrict__ out, int N) {
  int w = threadIdx.x >> 6;
  int lane = threadIdx.x & 63;
  int row0w = blockIdx.x * 64 + w * 16;
  int arow = row0w + (lane & 15);
  if (arow >= N) arow = N - 1;          // clamp (stores are guarded)
  const unsigned short* ap = gb + (size_t)arow * 512 + ((lane >> 4) << 3);

  f32x4 acc[4];
#pragma unroll
  for (int ct = 0; ct < 4; ++ct) {
    float bb = b2[ct * 16 + (lane & 15)];
    acc[ct][0] = bb; acc[ct][1] = bb; acc[ct][2] = bb; acc[ct][3] = bb;
  }

#pragma unroll 4
  for (int chunk = 0; chunk < 16; ++chunk) {
    bf16x8 a = *(const bf16x8*)(ap + chunk * 32);
    const unsigned short* bp = Bpack + ((size_t)chunk * 4 * 64 + lane) * 8;
#pragma unroll
    for (int ct = 0; ct < 4; ++ct) {
      bf16x8 b = *(const bf16x8*)(bp + (size_t)ct * 64 * 8);
      acc[ct] = __builtin_amdgcn_mfma_f32_16x16x32_bf16(a, b, acc[ct], 0, 0, 0);
    }
  }

  int orow0 = row0w + ((lane >> 4) << 2);
#pragma unroll
  for (int ct = 0; ct < 4; ++ct) {
    int col = ct * 16 + (lane & 15);
#pragma unroll
    for (int r = 0; r < 4; ++r) {
      int n = orow0 + r;
      if (n < N) out[(size_t)n * 64 + col] = acc[ct][r];
    }
  }
}

extern "C" void kernel_launch(void* const* d_in, const int* in_sizes, int n_in,
                              void* d_out, int out_size, void* d_ws, size_t ws_size,
                              hipStream_t stream) {
  const float* x     = (const float*)d_in[0];
  const void*  ei    = d_in[1];
  const float* W1    = (const float*)d_in[2];
  const float* attl1 = (const float*)d_in[3];
  const float* attr1 = (const float*)d_in[4];
  const float* b1    = (const float*)d_in[5];
  const float* W2    = (const float*)d_in[6];
  const float* attl2 = (const float*)d_in[7];
  const float* attr2 = (const float*)d_in[8];
  const float* b2    = (const float*)d_in[9];
  float* out = (float*)d_out;

  int N = in_sizes[0] / 128;
  int E = in_sizes[1] / 2;

  int nblk = (E + CHUNK - 1) / CHUNK;
  int nbk  = (N + (1 << BSHIFT) - 1) >> BSHIFT;
  int L    = nbk * nblk;

  char* ws = (char*)d_ws;
  size_t off = 0;
  auto alloc = [&](size_t bytes) {
    char* p = ws + off;
    off += (bytes + 255) & ~size_t(255);
    return p;
  };
  int*            edges   = (int*)alloc((size_t)2 * E * 4);
  int*            flag    = (int*)alloc(256);
  int*            deg     = (int*)alloc((size_t)N * 4);
  int*            cursor  = (int*)alloc((size_t)N * 4);
  int*            rowptr  = (int*)alloc((size_t)(N + 1) * 4);
  int*            bsum    = (int*)alloc(1024);
  int*            boff    = (int*)alloc(1024);
  int*            blkcnt  = (int*)alloc((size_t)L * 4);
  int*            basebuf = (int*)alloc((size_t)(L + 1) * 4);
  int*            bsum2   = (int*)alloc(1024);
  int*            boff2   = (int*)alloc(1024);
  long long*      binned  = (long long*)alloc((size_t)E * 8);
  int*            csr_src = (int*)alloc((size_t)E * 4);
  unsigned short* xl1b    = (unsigned short*)alloc((size_t)N * 64 * 2);
  float*          a1      = (float*)alloc((size_t)N * 16 * 4);
  unsigned short* hrb     = (unsigned short*)alloc((size_t)N * 64 * 2);
  float*          a2      = (float*)alloc((size_t)N * 16 * 4);
  float*          wl      = (float*)alloc(64 * 8 * 4);
  float*          wr      = (float*)alloc(64 * 8 * 4);
  unsigned short* Bpack   = (unsigned short*)alloc(512 * 64 * 2);
  unsigned short* W1pack  = (unsigned short*)alloc(128 * 64 * 2);
  unsigned short* gb      = (unsigned short*)alloc((size_t)N * 512 * 2);
  (void)ws_size;

  const int* srcp = edges;
  const int* dstp = edges + E;
  int SB  = (N + 1 + NT - 1) / NT;    // <= 256
  int SBL = (L + 1 + NT - 1) / NT;    // <= 256

  detect_kernel<<<1, NT, 0, stream>>>((const int*)ei, flag, 2 * E);
  cvt_edges_kernel<<<(2 * E + NT - 1) / NT, NT, 0, stream>>>(ei, edges, flag, 2 * E);
  zero2_kernel<<<(N + NT - 1) / NT, NT, 0, stream>>>(deg, cursor, N);

  // phase A: bucket-bin edges by dst>>BSHIFT (deterministic, bucket-contiguous)
  bincount_kernel<<<nblk, NT, 0, stream>>>(dstp, blkcnt, E, nblk, nbk);
  scan1_kernel<<<SBL, NT, 0, stream>>>(blkcnt, bsum2, L);
  scan2_kernel<<<1, NT, 0, stream>>>(bsum2, boff2, SBL);
  scan3_kernel<<<SBL, NT, 0, stream>>>(blkcnt, boff2, basebuf, L);
  binwrite_kernel<<<nblk, NT, 0, stream>>>(srcp, dstp, basebuf, binned, E, nblk, nbk);

  // degree histogram (bucket-local) + rowptr
  deghist_kernel<<<(E + NT - 1) / NT, NT, 0, stream>>>(binned, deg, E);
  scan1_kernel<<<SB, NT, 0, stream>>>(deg, bsum, N);
  scan2_kernel<<<1, NT, 0, stream>>>(bsum, boff, SB);
  scan3_kernel<<<SB, NT, 0, stream>>>(deg, boff, rowptr, N);

  // phase B: locality-friendly CSR scatter
  scatter2_kernel<<<(E + NT - 1) / NT, NT, 0, stream>>>(binned, rowptr, cursor, csr_src, E);

  // dense precomputation
  foldB1_kernel<<<(128 * 64 + NT - 1) / NT, NT, 0, stream>>>(W1, W1pack);
  gemm1_mfma_kernel<<<(N + 63) / 64, NT, 0, stream>>>(x, W1pack, attl1, attr1, xl1b, a1, N);
  foldw_kernel<<<1, 512, 0, stream>>>(W2, attl2, attr2, wl, wr);
  foldB_kernel<<<(512 * 64 + NT - 1) / NT, NT, 0, stream>>>(W2, Bpack);

  // layer 1 aggregation (+ fused relu/bias)
  node_aggr1_kernel<<<(N + 3) / 4, NT, 0, stream>>>(rowptr, csr_src, a1, xl1b, b1, hrb, N);

  // layer-2 attention dots (streaming)
  a2dots_kernel<<<(N + A2N - 1) / A2N, NT, 0, stream>>>(hrb, wl, wr, a2, N);

  // layer 2 aggregation -> g (bf16), then MFMA epilogue
  node_aggr2_kernel<<<(N + 3) / 4, NT, 0, stream>>>(rowptr, csr_src, a2, hrb, gb, N);
  gemm3_mfma_kernel<<<(N + 63) / 64, NT, 0, stream>>>(gb, Bpack, b2, out, N);
}